// Round 10
// baseline (322.801 us; speedup 1.0000x reference)
//
#include <hip/hip_runtime.h>
#include <hip/hip_bf16.h>
#include <math.h>

#define B_   2
#define N_   2000
#define T_   24
#define NX_  8
#define H_   64
#define G_   (B_*T_)        // 48 graphs
#define E_   32000
#define BN_  (B_*N_)        // 4000 sequences
#define TH_  (T_*H_)        // 1536
#define NTH_ (N_*T_*H_)     // 3072000
#define GNH_ (G_*N_*H_)     // 6144000
#define NPARAM_ 43340       // canonical fp32 param elements (x excluded)
#define NPARAM_PAD_ 43392
#define LSTM_PAD 72         // padded H-row (bf16 elems): 144B stride, 16B aligned, <=2-way banks

using bf16 = __hip_bfloat16;
typedef short bf16x8 __attribute__((ext_vector_type(8)));
typedef float f32x4  __attribute__((ext_vector_type(4)));

__device__ __forceinline__ float uasf(unsigned u){ return __uint_as_float(u); }
__device__ __forceinline__ float wave_sum(float v){
  #pragma unroll
  for (int o = 32; o > 0; o >>= 1) v += __shfl_xor(v, o, 64);
  return v;
}
__device__ __forceinline__ float half_sum(float v){
  #pragma unroll
  for (int o = 16; o > 0; o >>= 1) v += __shfl_xor(v, o, 64);
  return v;
}
__device__ __forceinline__ float half_max(float v){
  #pragma unroll
  for (int o = 16; o > 0; o >>= 1) v = fmaxf(v, __shfl_xor(v, o, 64));
  return v;
}
__device__ __forceinline__ float fastrcp(float x){ return __builtin_amdgcn_rcpf(x); }
__device__ __forceinline__ float sigf(float x){ return fastrcp(1.f + __expf(-x)); }
__device__ __forceinline__ float tanhfast(float x){ return 1.f - 2.f*fastrcp(1.f + __expf(2.f*x)); }
__device__ __forceinline__ float gelu_exact(float x){ return 0.5f*x*(1.f + erff(x*0.70710678118654752f)); }
__device__ __forceinline__ unsigned f2bf_rtn(float f){
  unsigned u = __float_as_uint(f);
  u += 0x7fffu + ((u >> 16) & 1u);
  return u >> 16;
}
__device__ __forceinline__ bf16x8 pack8(float4 a, float4 b){
  bf16x8 v;
  v[0]=(short)f2bf_rtn(a.x); v[1]=(short)f2bf_rtn(a.y);
  v[2]=(short)f2bf_rtn(a.z); v[3]=(short)f2bf_rtn(a.w);
  v[4]=(short)f2bf_rtn(b.x); v[5]=(short)f2bf_rtn(b.y);
  v[6]=(short)f2bf_rtn(b.z); v[7]=(short)f2bf_rtn(b.w);
  return v;
}

// ---------- prep: dtype detect + param convert + CSR build + Wc fold, ONE dispatch ----------
struct ConvArgs {
  const void* src[18];
  int off[19];
};
__global__ __launch_bounds__(256) void prep_kernel(
    ConvArgs a, const unsigned* __restrict__ xw,
    const int* __restrict__ esrc, const int* __restrict__ edst,
    float* __restrict__ dst, int* __restrict__ flag,
    int* __restrict__ offs, int* __restrict__ csrc,
    float* __restrict__ wc, float* __restrict__ bc){
  __shared__ int lcnt[N_];
  __shared__ int loffs[N_];
  __shared__ int cnt;
  int tid = threadIdx.x;
  // local dtype detection (every block; x region is L2-hot)
  if (tid == 0) cnt = 0;
  __syncthreads();
  int c = 0;
  for (int i = tid; i < 4096; i += 256){
    unsigned e = (xw[i] >> 7) & 0xffu;
    if (e >= 100u && e <= 140u) c++;
  }
  atomicAdd(&cnt, c);
  __syncthreads();
  int isbf = (cnt > 3276) ? 1 : 0;
  int bid = blockIdx.x;

  if (bid < 170){
    // param conversion
    if (bid == 0 && tid == 0) *flag = isbf;
    int i = bid*256 + tid;
    if (i < NPARAM_){
      int seg = 0;
      while (i >= a.off[seg+1]) seg++;
      int j = i - a.off[seg];
      float v;
      if (isbf) v = uasf(((unsigned)((const unsigned short*)a.src[seg])[j]) << 16);
      else      v = ((const float*)a.src[seg])[j];
      dst[i] = v;
    }
  } else if (bid == 170){
    // CSR build entirely in LDS: count -> scan -> fill
    for (int i = tid; i < N_; i += 256) lcnt[i] = 0;
    __syncthreads();
    for (int e = tid; e < E_; e += 256) atomicAdd(&lcnt[edst[e]], 1);
    __syncthreads();
    if (tid < 64){
      int lane = tid;
      int base = 0;
      for (int c0 = 0; c0 < N_; c0 += 64){
        int i = c0 + lane;
        int v = (i < N_) ? lcnt[i] : 0;
        int xv = v;
        #pragma unroll
        for (int o = 1; o < 64; o <<= 1){
          int y = __shfl_up(xv, o, 64);
          if (lane >= o) xv += y;
        }
        if (i < N_){ int ex = base + xv - v; loffs[i] = ex; offs[i] = ex; }
        base += __shfl(xv, 63, 64);
      }
      if (lane == 0) offs[N_] = base;
    }
    __syncthreads();
    for (int i = tid; i < N_; i += 256) lcnt[i] = 0;   // reuse as cursor
    __syncthreads();
    for (int e = tid; e < E_; e += 256){
      int d = edst[e];
      int pos = atomicAdd(&lcnt[d], 1);
      csrc[loffs[d] + pos] = esrc[e];
    }
  } else {
    // bid == 171: Wc = fcW @ g1W, bc = fcb @ g1W (inline dtype conversion)
    const void* pfcW = a.src[0];
    const void* pfcb = a.src[1];
    const void* pg1W = a.src[2];
    #pragma unroll
    for (int half = 0; half < 2; ++half){
      int t2 = half*256 + tid;              // 0..511
      int i = t2 >> 6, n = t2 & 63;
      float s = 0.f;
      for (int k = 0; k < 64; ++k){
        float fa = isbf ? uasf(((unsigned)((const unsigned short*)pfcW)[i*64+k]) << 16)
                        : ((const float*)pfcW)[i*64+k];
        float fb = isbf ? uasf(((unsigned)((const unsigned short*)pg1W)[k*64+n]) << 16)
                        : ((const float*)pg1W)[k*64+n];
        s = fmaf(fa, fb, s);
      }
      wc[i*64 + n] = s;
    }
    if (tid < 64){
      float b = 0.f;
      for (int k = 0; k < 64; ++k){
        float fa = isbf ? uasf(((unsigned)((const unsigned short*)pfcb)[k]) << 16)
                        : ((const float*)pfcb)[k];
        float fb = isbf ? uasf(((unsigned)((const unsigned short*)pg1W)[k*64+tid]) << 16)
                        : ((const float*)pg1W)[k*64+tid];
        b = fmaf(fa, fb, b);
      }
      bc[tid] = b;
    }
  }
}

// ---------- GAT1 fused: h = x @ Wc + bc via MFMA (K=8 in K=32 slot) ----------
__global__ __launch_bounds__(256) void gat_h1_fused_kernel(
    const void* __restrict__ xraw, const int* __restrict__ flag,
    const float* __restrict__ wc, const float* __restrict__ bc,
    const float* __restrict__ asrc, const float* __restrict__ adst,
    unsigned short* __restrict__ hbuf, float* __restrict__ es, float* __restrict__ ed){
  int lane = threadIdx.x & 63, wave = threadIdx.x >> 6;
  int q = lane >> 4, c = lane & 15;
  int isbf = *flag;
  bf16x8 Bf[4];                       // B[n=c][k=q*8+j]; only q==0 rows of Wc nonzero
  #pragma unroll
  for (int nt = 0; nt < 4; ++nt){
    bf16x8 v;
    #pragma unroll
    for (int j = 0; j < 8; ++j)
      v[j] = (q == 0) ? (short)f2bf_rtn(wc[j*64 + nt*16 + c]) : (short)0;
    Bf[nt] = v;
  }
  float bcv[4];
  #pragma unroll
  for (int nt = 0; nt < 4; ++nt) bcv[nt] = bc[nt*16 + c];
  float aS[4], aD[4];
  #pragma unroll
  for (int nt = 0; nt < 4; ++nt){ aS[nt] = asrc[nt*16+c]; aD[nt] = adst[nt*16+c]; }

  int w = blockIdx.x*4 + wave;        // 750*4 = 3000 waves, 2 tiles each
  #pragma unroll
  for (int it = 0; it < 2; ++it){
    int tile = w*2 + it;
    int p0 = tile*16;
    int g  = p0 / N_, n0 = p0 - g*N_;
    int bb = g / T_,  tt = g - bb*T_;
    bf16x8 A0;
    #pragma unroll
    for (int j = 0; j < 8; ++j) A0[j] = 0;
    if (q == 0){
      size_t rowelt = ((size_t)(bb*N_ + n0 + c)*T_ + tt)*NX_;
      if (isbf){
        A0 = *(const bf16x8*)((const unsigned short*)xraw + rowelt);
      } else {
        const float4* xr4 = (const float4*)((const float*)xraw + rowelt);
        A0 = pack8(xr4[0], xr4[1]);
      }
    }
    f32x4 acc[4];
    #pragma unroll
    for (int nt = 0; nt < 4; ++nt){ acc[nt][0]=bcv[nt]; acc[nt][1]=bcv[nt]; acc[nt][2]=bcv[nt]; acc[nt][3]=bcv[nt]; }
    #pragma unroll
    for (int nt = 0; nt < 4; ++nt) acc[nt] = __builtin_amdgcn_mfma_f32_16x16x32_bf16(A0, Bf[nt], acc[nt], 0, 0, 0);

    #pragma unroll
    for (int nt = 0; nt < 4; ++nt){
      #pragma unroll
      for (int r = 0; r < 4; ++r)
        hbuf[(size_t)(p0 + q*4 + r)*H_ + nt*16 + c] = (unsigned short)f2bf_rtn(acc[nt][r]);
    }
    #pragma unroll
    for (int r = 0; r < 4; ++r){
      float e1 = acc[0][r]*aS[0] + acc[1][r]*aS[1] + acc[2][r]*aS[2] + acc[3][r]*aS[3];
      float e2 = acc[0][r]*aD[0] + acc[1][r]*aD[1] + acc[2][r]*aD[2] + acc[3][r]*aD[3];
      #pragma unroll
      for (int o = 8; o > 0; o >>= 1){
        e1 += __shfl_xor(e1, o, 64);
        e2 += __shfl_xor(e2, o, 64);
      }
      if (c == 0){
        es[p0 + q*4 + r] = e1;
        ed[p0 + q*4 + r] = e2;
      }
    }
  }
}

// ---------- GAT2 h = gout1 @ W via MFMA (scrambled raw-reshape reads) ----------
__global__ __launch_bounds__(256) void gat_h2_mfma_kernel(
    const float* __restrict__ xin, const float* __restrict__ W,
    const float* __restrict__ asrc, const float* __restrict__ adst,
    unsigned short* __restrict__ hbuf, float* __restrict__ es, float* __restrict__ ed){
  int lane = threadIdx.x & 63, wave = threadIdx.x >> 6;
  int q = lane >> 4, c = lane & 15;
  bf16x8 Bf[4][2];
  #pragma unroll
  for (int nt = 0; nt < 4; ++nt){
    #pragma unroll
    for (int ks = 0; ks < 2; ++ks){
      bf16x8 v;
      #pragma unroll
      for (int j = 0; j < 8; ++j)
        v[j] = (short)f2bf_rtn(W[(ks*32 + q*8 + j)*H_ + nt*16 + c]);
      Bf[nt][ks] = v;
    }
  }
  float aS[4], aD[4];
  #pragma unroll
  for (int nt = 0; nt < 4; ++nt){ aS[nt] = asrc[nt*16+c]; aD[nt] = adst[nt*16+c]; }

  int w = blockIdx.x*4 + wave;
  #pragma unroll
  for (int it = 0; it < 2; ++it){
    int tile = w*2 + it;
    int p0 = tile*16;
    int p  = p0 + c;
    int g = p / N_, n = p - g*N_;
    int bb = g / T_, t = g - bb*T_;
    const float4* xr4 = (const float4*)(xin + (size_t)bb*NTH_ + (size_t)n*TH_ + (size_t)t*H_);
    float4 x0 = xr4[q*2],     x1 = xr4[q*2 + 1];
    float4 x2 = xr4[8 + q*2], x3 = xr4[8 + q*2 + 1];
    bf16x8 A0 = pack8(x0, x1);
    bf16x8 A1 = pack8(x2, x3);

    f32x4 acc[4];
    #pragma unroll
    for (int nt = 0; nt < 4; ++nt){ acc[nt][0]=0.f; acc[nt][1]=0.f; acc[nt][2]=0.f; acc[nt][3]=0.f; }
    #pragma unroll
    for (int nt = 0; nt < 4; ++nt) acc[nt] = __builtin_amdgcn_mfma_f32_16x16x32_bf16(A0, Bf[nt][0], acc[nt], 0, 0, 0);
    #pragma unroll
    for (int nt = 0; nt < 4; ++nt) acc[nt] = __builtin_amdgcn_mfma_f32_16x16x32_bf16(A1, Bf[nt][1], acc[nt], 0, 0, 0);

    #pragma unroll
    for (int nt = 0; nt < 4; ++nt){
      #pragma unroll
      for (int r = 0; r < 4; ++r)
        hbuf[(size_t)(p0 + q*4 + r)*H_ + nt*16 + c] = (unsigned short)f2bf_rtn(acc[nt][r]);
    }
    #pragma unroll
    for (int r = 0; r < 4; ++r){
      float e1 = acc[0][r]*aS[0] + acc[1][r]*aS[1] + acc[2][r]*aS[2] + acc[3][r]*aS[3];
      float e2 = acc[0][r]*aD[0] + acc[1][r]*aD[1] + acc[2][r]*aD[2] + acc[3][r]*aD[3];
      #pragma unroll
      for (int o = 8; o > 0; o >>= 1){
        e1 += __shfl_xor(e1, o, 64);
        e2 += __shfl_xor(e2, o, 64);
      }
      if (c == 0){
        es[p0 + q*4 + r] = e1;
        ed[p0 + q*4 + r] = e2;
      }
    }
  }
}

// ---------- GAT aggregate: 2 (g,d) per wave, 2 channels/lane, dword gathers ----------
__global__ __launch_bounds__(256) void gat_agg_kernel(
    const unsigned short* __restrict__ hbuf, const float* __restrict__ es, const float* __restrict__ ed,
    const int* __restrict__ offs, const int* __restrict__ csrc,
    const float* __restrict__ bias, float* __restrict__ gout){
  int lane = threadIdx.x & 63, wave = threadIdx.x >> 6;
  int h = lane >> 5, ln = lane & 31;
  int gd = (blockIdx.x*4 + wave)*2 + h;   // 12000 blocks -> 96000 pairs
  int g = gd / N_, d = gd - g*N_;
  int start = offs[d], deg = offs[d+1] - start;
  const float* esg = es + (size_t)g*N_;
  float edv = ed[(size_t)g*N_ + d];
  const char* hg = (const char*)(hbuf + (size_t)g*N_*H_);
  unsigned lanoff = ((unsigned)ln) << 2;
  int hbase = h << 5;
  int dm = max(deg, __shfl_xor(deg, 32, 64));   // wave-uniform max degree

  float acc0 = 0.f, acc1 = 0.f;
  if (dm <= 32){
    int sv = 0; float sc = -1e30f;
    if (ln < deg){
      sv = csrc[start + ln];
      float e = esg[sv] + edv;
      sc = e > 0.f ? e : 0.2f*e;
    }
    float m = half_max(sc);
    float ex = (ln < deg) ? __expf(sc - m) : 0.f;
    float ssum = half_sum(ex);
    ex *= fastrcp(ssum + 1e-16f);
    unsigned pw = (f2bf_rtn(ex) << 16) | (unsigned)sv;   // alpha(bf16) | src_id
    for (int j0 = 0; j0 < dm; j0 += 8){
      unsigned wv[8]; float aa[8]; unsigned off[8];
      #pragma unroll
      for (int u = 0; u < 8; ++u){
        int j = j0 + u;
        wv[u] = (unsigned)__shfl((int)pw, hbase + j, 64);
        aa[u] = (j < deg) ? uasf(wv[u] & 0xffff0000u) : 0.f;
        off[u] = ((wv[u] & 0xffffu) << 7) + lanoff;
      }
      unsigned hv[8];
      #pragma unroll
      for (int u = 0; u < 8; ++u)
        hv[u] = *(const unsigned*)(hg + off[u]);
      #pragma unroll
      for (int u = 0; u < 8; ++u){
        acc0 = fmaf(aa[u], uasf(hv[u] << 16), acc0);
        acc1 = fmaf(aa[u], uasf(hv[u] & 0xffff0000u), acc1);
      }
    }
  } else {
    // general chunked path (deg > 32): 32-wide chunks per half
    float m = -1e30f;
    for (int base = 0; base < deg; base += 32){
      int i = base + ln;
      if (i < deg){
        int s = csrc[start + i];
        float e = esg[s] + edv;
        float t = e > 0.f ? e : 0.2f*e;
        m = fmaxf(m, t);
      }
    }
    m = half_max(m);
    float ssum = 0.f;
    for (int base = 0; base < deg; base += 32){
      int i = base + ln;
      if (i < deg){
        int s = csrc[start + i];
        float e = esg[s] + edv;
        float t = e > 0.f ? e : 0.2f*e;
        ssum += __expf(t - m);
      }
    }
    ssum = half_sum(ssum);
    float inv = fastrcp(ssum + 1e-16f);
    for (int base = 0; base < dm; base += 32){
      int i = base + ln;
      int sv = 0; float ex = 0.f;
      if (i < deg){
        sv = csrc[start + i];
        float e = esg[sv] + edv;
        float t = e > 0.f ? e : 0.2f*e;
        ex = __expf(t - m) * inv;
      }
      unsigned pw = (f2bf_rtn(ex) << 16) | (unsigned)sv;
      int rem = dm - base; if (rem > 32) rem = 32;
      int myrem = deg - base;
      for (int j0 = 0; j0 < rem; j0 += 8){
        unsigned wv[8]; float aa[8]; unsigned off[8];
        #pragma unroll
        for (int u = 0; u < 8; ++u){
          int j = j0 + u;
          wv[u] = (unsigned)__shfl((int)pw, hbase + j, 64);
          aa[u] = (j < myrem) ? uasf(wv[u] & 0xffff0000u) : 0.f;
          off[u] = ((wv[u] & 0xffffu) << 7) + lanoff;
        }
        unsigned hv[8];
        #pragma unroll
        for (int u = 0; u < 8; ++u)
          hv[u] = *(const unsigned*)(hg + off[u]);
        #pragma unroll
        for (int u = 0; u < 8; ++u){
          acc0 = fmaf(aa[u], uasf(hv[u] << 16), acc0);
          acc1 = fmaf(aa[u], uasf(hv[u] & 0xffff0000u), acc1);
        }
      }
    }
  }
  float2 bv = ((const float2*)bias)[ln];
  float2 o2;
  o2.x = gelu_exact(acc0 + bv.x);
  o2.y = gelu_exact(acc1 + bv.y);
  ((float2*)(gout + (size_t)gd*H_))[ln] = o2;
}

// ---------- LSTM via MFMA + fused LayerNorm/dense epilogue ----------
__global__ __launch_bounds__(256) void lstm_final_kernel(
    const float* __restrict__ xin,   // flat [BN*T, 64]: row = seq*T + t
    const float* __restrict__ Wih,   // [256][64] row-major
    const float* __restrict__ Whh,   // [256][64] row-major
    const float* __restrict__ bih, const float* __restrict__ bhh,
    const float* __restrict__ lng, const float* __restrict__ lnb,
    const float* __restrict__ dW, const float* __restrict__ db,
    const int* __restrict__ flag, void* __restrict__ outv){
  __shared__ __align__(16) unsigned short Hlds[16*LSTM_PAD];
  __shared__ float smH[16][68];      // +4 pad: conflict-light
  int tid = threadIdx.x;
  int lane = tid & 63, wave = tid >> 6;
  int q = lane >> 4, c = lane & 15;
  int s0 = blockIdx.x * 16;

  bf16x8 Bf[4][4];
  #pragma unroll
  for (int g = 0; g < 4; ++g){
    int n = g*64 + wave*16 + c;
    #pragma unroll
    for (int ks = 0; ks < 4; ++ks){
      const float* srcp = (ks < 2) ? (Whh + (size_t)n*64 + ks*32 + q*8)
                                   : (Wih + (size_t)n*64 + (ks-2)*32 + q*8);
      float4 a = ((const float4*)srcp)[0];
      float4 b = ((const float4*)srcp)[1];
      Bf[g][ks] = pack8(a, b);
    }
  }
  float bsum[4];
  #pragma unroll
  for (int g = 0; g < 4; ++g){
    int n = g*64 + wave*16 + c;
    bsum[g] = bih[n] + bhh[n];
  }
  for (int i = tid; i < 16*LSTM_PAD; i += 256) Hlds[i] = 0;
  float cst[4] = {0.f, 0.f, 0.f, 0.f};
  __syncthreads();

  for (int t = 0; t < T_; ++t){
    const float4* xr4 = (const float4*)(xin + ((size_t)(s0 + c)*T_ + t)*64);
    float4 x0 = xr4[q*2],     x1 = xr4[q*2 + 1];
    float4 x2 = xr4[8 + q*2], x3 = xr4[8 + q*2 + 1];
    bf16x8 Ax0 = pack8(x0, x1);
    bf16x8 Ax1 = pack8(x2, x3);
    const bf16x8* hrow = (const bf16x8*)(Hlds + c*LSTM_PAD);
    bf16x8 Ah0 = hrow[q];
    bf16x8 Ah1 = hrow[4 + q];

    f32x4 acc[4];
    #pragma unroll
    for (int g = 0; g < 4; ++g){ acc[g][0]=bsum[g]; acc[g][1]=bsum[g]; acc[g][2]=bsum[g]; acc[g][3]=bsum[g]; }
    #pragma unroll
    for (int g = 0; g < 4; ++g) acc[g] = __builtin_amdgcn_mfma_f32_16x16x32_bf16(Ah0, Bf[g][0], acc[g], 0, 0, 0);
    #pragma unroll
    for (int g = 0; g < 4; ++g) acc[g] = __builtin_amdgcn_mfma_f32_16x16x32_bf16(Ah1, Bf[g][1], acc[g], 0, 0, 0);
    #pragma unroll
    for (int g = 0; g < 4; ++g) acc[g] = __builtin_amdgcn_mfma_f32_16x16x32_bf16(Ax0, Bf[g][2], acc[g], 0, 0, 0);
    #pragma unroll
    for (int g = 0; g < 4; ++g) acc[g] = __builtin_amdgcn_mfma_f32_16x16x32_bf16(Ax1, Bf[g][3], acc[g], 0, 0, 0);

    float hv[4];
    #pragma unroll
    for (int r = 0; r < 4; ++r){
      float zi = acc[0][r], zf = acc[1][r], zg = acc[2][r], zo = acc[3][r];
      cst[r] = sigf(zf)*cst[r] + sigf(zi)*tanhfast(zg);
      hv[r] = sigf(zo)*tanhfast(cst[r]);
    }
    if (t == T_-1){
      #pragma unroll
      for (int r = 0; r < 4; ++r)
        smH[q*4 + r][wave*16 + c] = hv[r];
    } else {
      __syncthreads();
      #pragma unroll
      for (int r = 0; r < 4; ++r)
        Hlds[(q*4 + r)*LSTM_PAD + wave*16 + c] = (unsigned short)f2bf_rtn(hv[r]);
      __syncthreads();
    }
  }
  __syncthreads();

  // fused LayerNorm + dense[64,12]; wave w handles seqs 4w..4w+3
  int isbf = *flag;
  #pragma unroll
  for (int si = 0; si < 4; ++si){
    int s = wave*4 + si;
    float h = smH[s][lane];
    float mu = wave_sum(h) * (1.f/64.f);
    float dev = h - mu;
    float var = wave_sum(dev*dev) * (1.f/64.f);
    float hn = dev * rsqrtf(var + 1e-5f) * lng[lane] + lnb[lane];
    smH[s][lane] = hn;       // wave-internal write->read, in-order LDS
    if (lane < 12){
      float o = db[lane];
      #pragma unroll
      for (int k = 0; k < 64; ++k) o = fmaf(smH[s][k], dW[k*12 + lane], o);
      size_t oi = (size_t)(s0 + s)*12 + lane;
      if (isbf) ((unsigned short*)outv)[oi] = (unsigned short)f2bf_rtn(o);
      else      ((float*)outv)[oi] = o;
    }
  }
}

extern "C" void kernel_launch(void* const* d_in, const int* in_sizes, int n_in,
                              void* d_out, int out_size, void* d_ws, size_t ws_size,
                              hipStream_t stream) {
  const int* esrc = (const int*)d_in[1];
  const int* edst = (const int*)d_in[2];

  static const int sizes[18] = {512, 64, 4096, 64, 64, 64, 4096, 64, 64, 64,
                                16384, 16384, 256, 256, 64, 64, 768, 12};
  static const int srcidx[18] = {3, 4, 5, 6, 7, 8, 9, 10, 11, 12,
                                 13, 14, 15, 16, 17, 18, 19, 20};
  ConvArgs ca;
  {
    int acc = 0;
    for (int i = 0; i < 18; ++i){ ca.src[i] = d_in[srcidx[i]]; ca.off[i] = acc; acc += sizes[i]; }
    ca.off[18] = acc;   // == NPARAM_
  }

  float* P     = (float*)d_ws;               // [NPARAM_PAD_]
  float* bufA  = P + NPARAM_PAD_;            // gout1 -> g2out
  float* bufB  = bufA + (size_t)GNH_;        // hbuf(bf16)
  float* esb   = bufB + (size_t)GNH_;
  float* edb   = esb  + (size_t)G_*N_;
  int*   offs  = (int*)(edb + (size_t)G_*N_);// [N_+1]
  int*   csrc  = offs + (N_ + 1);            // [E_]
  int*   flag  = csrc + E_;                  // [1]
  float* wcb   = (float*)(flag + 1);         // Wc[512] + bc[64]
  unsigned short* hbuf = (unsigned short*)bufB;

  const float* pg1b = P + 4672;
  const float* pg1as= P + 4736;
  const float* pg1ad= P + 4800;
  const float* pg2W = P + 4864;
  const float* pg2b = P + 8960;
  const float* pg2as= P + 9024;
  const float* pg2ad= P + 9088;
  const float* pWih = P + 9152;
  const float* pWhh = P + 25536;
  const float* pbih = P + 41920;
  const float* pbhh = P + 42176;
  const float* plng = P + 42432;
  const float* plnb = P + 42496;
  const float* pdW  = P + 42560;
  const float* pdb  = P + 43328;

  prep_kernel<<<172, 256, 0, stream>>>(ca, (const unsigned*)d_in[0], esrc, edst,
                                       P, flag, offs, csrc, wcb, wcb + 512);

  gat_h1_fused_kernel<<<750, 256, 0, stream>>>(d_in[0], flag, wcb, wcb + 512,
                                               pg1as, pg1ad, hbuf, esb, edb);
  gat_agg_kernel<<<12000, 256, 0, stream>>>(hbuf, esb, edb, offs, csrc, pg1b, bufA);

  gat_h2_mfma_kernel<<<750, 256, 0, stream>>>(bufA, pg2W, pg2as, pg2ad, hbuf, esb, edb);
  gat_agg_kernel<<<12000, 256, 0, stream>>>(hbuf, esb, edb, offs, csrc, pg2b, bufA);

  lstm_final_kernel<<<250, 256, 0, stream>>>(bufA, pWih, pWhh, pbih, pbhh,
                                             plng, plnb, pdW, pdb, flag, d_out);
}

// Round 11
// 247.091 us; speedup vs baseline: 1.3064x; 1.3064x over previous
//
#include <hip/hip_runtime.h>
#include <hip/hip_bf16.h>
#include <math.h>

#define B_   2
#define N_   2000
#define T_   24
#define NX_  8
#define H_   64
#define G_   (B_*T_)        // 48 graphs
#define E_   32000
#define BN_  (B_*N_)        // 4000 sequences
#define TH_  (T_*H_)        // 1536
#define NTH_ (N_*T_*H_)     // 3072000
#define GNH_ (G_*N_*H_)     // 6144000
#define NPARAM_ 43340       // canonical fp32 param elements (x excluded)
#define NPARAM_PAD_ 43392
#define LSTM_PAD 72         // padded H-row (bf16 elems): 144B stride, 16B aligned, <=2-way banks
#define DEGCAP 64           // slot capacity per dst node (max binomial deg ~35)

using bf16 = __hip_bfloat16;
typedef short bf16x8 __attribute__((ext_vector_type(8)));
typedef float f32x4  __attribute__((ext_vector_type(4)));

__device__ __forceinline__ float uasf(unsigned u){ return __uint_as_float(u); }
__device__ __forceinline__ float wave_sum(float v){
  #pragma unroll
  for (int o = 32; o > 0; o >>= 1) v += __shfl_xor(v, o, 64);
  return v;
}
__device__ __forceinline__ float half_sum(float v){
  #pragma unroll
  for (int o = 16; o > 0; o >>= 1) v += __shfl_xor(v, o, 64);
  return v;
}
__device__ __forceinline__ float half_max(float v){
  #pragma unroll
  for (int o = 16; o > 0; o >>= 1) v = fmaxf(v, __shfl_xor(v, o, 64));
  return v;
}
__device__ __forceinline__ float fastrcp(float x){ return __builtin_amdgcn_rcpf(x); }
__device__ __forceinline__ float sigf(float x){ return fastrcp(1.f + __expf(-x)); }
__device__ __forceinline__ float tanhfast(float x){ return 1.f - 2.f*fastrcp(1.f + __expf(2.f*x)); }
__device__ __forceinline__ float gelu_exact(float x){ return 0.5f*x*(1.f + erff(x*0.70710678118654752f)); }
__device__ __forceinline__ unsigned f2bf_rtn(float f){
  unsigned u = __float_as_uint(f);
  u += 0x7fffu + ((u >> 16) & 1u);
  return u >> 16;
}
__device__ __forceinline__ bf16x8 pack8(float4 a, float4 b){
  bf16x8 v;
  v[0]=(short)f2bf_rtn(a.x); v[1]=(short)f2bf_rtn(a.y);
  v[2]=(short)f2bf_rtn(a.z); v[3]=(short)f2bf_rtn(a.w);
  v[4]=(short)f2bf_rtn(b.x); v[5]=(short)f2bf_rtn(b.y);
  v[6]=(short)f2bf_rtn(b.z); v[7]=(short)f2bf_rtn(b.w);
  return v;
}

// ---------- prep: dtype detect + param convert + cnt zero + Wc fold, ONE dispatch ----------
// No single-block memory-parallel work: every block's job is small and parallel.
struct ConvArgs {
  const void* src[18];
  int off[19];
};
__global__ __launch_bounds__(256) void prep_kernel(
    ConvArgs a, const unsigned* __restrict__ xw,
    float* __restrict__ dst, int* __restrict__ flag,
    int* __restrict__ cnt_g,
    float* __restrict__ wc, float* __restrict__ bc){
  __shared__ int scnt;
  int tid = threadIdx.x;
  if (tid == 0) scnt = 0;
  __syncthreads();
  int c = 0;
  for (int i = tid; i < 4096; i += 256){
    unsigned e = (xw[i] >> 7) & 0xffu;
    if (e >= 100u && e <= 140u) c++;
  }
  atomicAdd(&scnt, c);
  __syncthreads();
  int isbf = (scnt > 3276) ? 1 : 0;
  int bid = blockIdx.x;

  if (bid < 170){
    if (bid == 0 && tid == 0) *flag = isbf;
    int i = bid*256 + tid;
    if (i < NPARAM_){
      int seg = 0;
      while (i >= a.off[seg+1]) seg++;
      int j = i - a.off[seg];
      float v;
      if (isbf) v = uasf(((unsigned)((const unsigned short*)a.src[seg])[j]) << 16);
      else      v = ((const float*)a.src[seg])[j];
      dst[i] = v;
    }
  } else if (bid == 170){
    for (int i = tid; i < N_; i += 256) cnt_g[i] = 0;
  } else {
    // bid == 171: Wc = fcW @ g1W, bc = fcb @ g1W (inline dtype conversion)
    const void* pfcW = a.src[0];
    const void* pfcb = a.src[1];
    const void* pg1W = a.src[2];
    #pragma unroll
    for (int half = 0; half < 2; ++half){
      int t2 = half*256 + tid;              // 0..511
      int i = t2 >> 6, n = t2 & 63;
      float s = 0.f;
      #pragma unroll
      for (int k = 0; k < 64; ++k){
        float fa = isbf ? uasf(((unsigned)((const unsigned short*)pfcW)[i*64+k]) << 16)
                        : ((const float*)pfcW)[i*64+k];
        float fb = isbf ? uasf(((unsigned)((const unsigned short*)pg1W)[k*64+n]) << 16)
                        : ((const float*)pg1W)[k*64+n];
        s = fmaf(fa, fb, s);
      }
      wc[i*64 + n] = s;
    }
    if (tid < 64){
      float b = 0.f;
      #pragma unroll
      for (int k = 0; k < 64; ++k){
        float fa = isbf ? uasf(((unsigned)((const unsigned short*)pfcb)[k]) << 16)
                        : ((const float*)pfcb)[k];
        float fb = isbf ? uasf(((unsigned)((const unsigned short*)pg1W)[k*64+tid]) << 16)
                        : ((const float*)pg1W)[k*64+tid];
        b = fmaf(fa, fb, b);
      }
      bc[tid] = b;
    }
  }
}

// ---------- GAT1 fused: edge-table build (blocks 0..124) + h = x @ Wc + bc via MFMA ----------
__global__ __launch_bounds__(256) void gat_h1_fused_kernel(
    const void* __restrict__ xraw, const int* __restrict__ flag,
    const int* __restrict__ esrc, const int* __restrict__ edst,
    int* __restrict__ cnt_g, int* __restrict__ slot,
    const float* __restrict__ wc, const float* __restrict__ bc,
    const float* __restrict__ asrc, const float* __restrict__ adst,
    unsigned short* __restrict__ hbuf, float* __restrict__ es, float* __restrict__ ed){
  // edge build: 125 blocks x 256 edges, fully parallel, overlapped with MFMA blocks
  if (blockIdx.x < 125){
    int e = blockIdx.x*256 + threadIdx.x;      // exactly covers E_=32000
    int d = edst[e];
    int pos = atomicAdd(&cnt_g[d], 1);
    if (pos < DEGCAP) slot[(d << 6) + pos] = esrc[e];
  }
  int lane = threadIdx.x & 63, wave = threadIdx.x >> 6;
  int q = lane >> 4, c = lane & 15;
  int isbf = *flag;
  bf16x8 Bf[4];                       // B[n=c][k=q*8+j]; only q==0 rows of Wc nonzero
  #pragma unroll
  for (int nt = 0; nt < 4; ++nt){
    bf16x8 v;
    #pragma unroll
    for (int j = 0; j < 8; ++j)
      v[j] = (q == 0) ? (short)f2bf_rtn(wc[j*64 + nt*16 + c]) : (short)0;
    Bf[nt] = v;
  }
  float bcv[4];
  #pragma unroll
  for (int nt = 0; nt < 4; ++nt) bcv[nt] = bc[nt*16 + c];
  float aS[4], aD[4];
  #pragma unroll
  for (int nt = 0; nt < 4; ++nt){ aS[nt] = asrc[nt*16+c]; aD[nt] = adst[nt*16+c]; }

  int w = blockIdx.x*4 + wave;        // 750*4 = 3000 waves, 2 tiles each
  #pragma unroll
  for (int it = 0; it < 2; ++it){
    int tile = w*2 + it;
    int p0 = tile*16;
    int g  = p0 / N_, n0 = p0 - g*N_;
    int bb = g / T_,  tt = g - bb*T_;
    bf16x8 A0;
    #pragma unroll
    for (int j = 0; j < 8; ++j) A0[j] = 0;
    if (q == 0){
      size_t rowelt = ((size_t)(bb*N_ + n0 + c)*T_ + tt)*NX_;
      if (isbf){
        A0 = *(const bf16x8*)((const unsigned short*)xraw + rowelt);
      } else {
        const float4* xr4 = (const float4*)((const float*)xraw + rowelt);
        A0 = pack8(xr4[0], xr4[1]);
      }
    }
    f32x4 acc[4];
    #pragma unroll
    for (int nt = 0; nt < 4; ++nt){ acc[nt][0]=bcv[nt]; acc[nt][1]=bcv[nt]; acc[nt][2]=bcv[nt]; acc[nt][3]=bcv[nt]; }
    #pragma unroll
    for (int nt = 0; nt < 4; ++nt) acc[nt] = __builtin_amdgcn_mfma_f32_16x16x32_bf16(A0, Bf[nt], acc[nt], 0, 0, 0);

    #pragma unroll
    for (int nt = 0; nt < 4; ++nt){
      #pragma unroll
      for (int r = 0; r < 4; ++r)
        hbuf[(size_t)(p0 + q*4 + r)*H_ + nt*16 + c] = (unsigned short)f2bf_rtn(acc[nt][r]);
    }
    #pragma unroll
    for (int r = 0; r < 4; ++r){
      float e1 = acc[0][r]*aS[0] + acc[1][r]*aS[1] + acc[2][r]*aS[2] + acc[3][r]*aS[3];
      float e2 = acc[0][r]*aD[0] + acc[1][r]*aD[1] + acc[2][r]*aD[2] + acc[3][r]*aD[3];
      #pragma unroll
      for (int o = 8; o > 0; o >>= 1){
        e1 += __shfl_xor(e1, o, 64);
        e2 += __shfl_xor(e2, o, 64);
      }
      if (c == 0){
        es[p0 + q*4 + r] = e1;
        ed[p0 + q*4 + r] = e2;
      }
    }
  }
}

// ---------- GAT2 h = gout1 @ W via MFMA (scrambled raw-reshape reads) ----------
__global__ __launch_bounds__(256) void gat_h2_mfma_kernel(
    const float* __restrict__ xin, const float* __restrict__ W,
    const float* __restrict__ asrc, const float* __restrict__ adst,
    unsigned short* __restrict__ hbuf, float* __restrict__ es, float* __restrict__ ed){
  int lane = threadIdx.x & 63, wave = threadIdx.x >> 6;
  int q = lane >> 4, c = lane & 15;
  bf16x8 Bf[4][2];
  #pragma unroll
  for (int nt = 0; nt < 4; ++nt){
    #pragma unroll
    for (int ks = 0; ks < 2; ++ks){
      bf16x8 v;
      #pragma unroll
      for (int j = 0; j < 8; ++j)
        v[j] = (short)f2bf_rtn(W[(ks*32 + q*8 + j)*H_ + nt*16 + c]);
      Bf[nt][ks] = v;
    }
  }
  float aS[4], aD[4];
  #pragma unroll
  for (int nt = 0; nt < 4; ++nt){ aS[nt] = asrc[nt*16+c]; aD[nt] = adst[nt*16+c]; }

  int w = blockIdx.x*4 + wave;
  #pragma unroll
  for (int it = 0; it < 2; ++it){
    int tile = w*2 + it;
    int p0 = tile*16;
    int p  = p0 + c;
    int g = p / N_, n = p - g*N_;
    int bb = g / T_, t = g - bb*T_;
    const float4* xr4 = (const float4*)(xin + (size_t)bb*NTH_ + (size_t)n*TH_ + (size_t)t*H_);
    float4 x0 = xr4[q*2],     x1 = xr4[q*2 + 1];
    float4 x2 = xr4[8 + q*2], x3 = xr4[8 + q*2 + 1];
    bf16x8 A0 = pack8(x0, x1);
    bf16x8 A1 = pack8(x2, x3);

    f32x4 acc[4];
    #pragma unroll
    for (int nt = 0; nt < 4; ++nt){ acc[nt][0]=0.f; acc[nt][1]=0.f; acc[nt][2]=0.f; acc[nt][3]=0.f; }
    #pragma unroll
    for (int nt = 0; nt < 4; ++nt) acc[nt] = __builtin_amdgcn_mfma_f32_16x16x32_bf16(A0, Bf[nt][0], acc[nt], 0, 0, 0);
    #pragma unroll
    for (int nt = 0; nt < 4; ++nt) acc[nt] = __builtin_amdgcn_mfma_f32_16x16x32_bf16(A1, Bf[nt][1], acc[nt], 0, 0, 0);

    #pragma unroll
    for (int nt = 0; nt < 4; ++nt){
      #pragma unroll
      for (int r = 0; r < 4; ++r)
        hbuf[(size_t)(p0 + q*4 + r)*H_ + nt*16 + c] = (unsigned short)f2bf_rtn(acc[nt][r]);
    }
    #pragma unroll
    for (int r = 0; r < 4; ++r){
      float e1 = acc[0][r]*aS[0] + acc[1][r]*aS[1] + acc[2][r]*aS[2] + acc[3][r]*aS[3];
      float e2 = acc[0][r]*aD[0] + acc[1][r]*aD[1] + acc[2][r]*aD[2] + acc[3][r]*aD[3];
      #pragma unroll
      for (int o = 8; o > 0; o >>= 1){
        e1 += __shfl_xor(e1, o, 64);
        e2 += __shfl_xor(e2, o, 64);
      }
      if (c == 0){
        es[p0 + q*4 + r] = e1;
        ed[p0 + q*4 + r] = e2;
      }
    }
  }
}

// ---------- GAT aggregate: 2 (g,d) per wave, 2 channels/lane, slot-table edges ----------
__global__ __launch_bounds__(256) void gat_agg_kernel(
    const unsigned short* __restrict__ hbuf, const float* __restrict__ es, const float* __restrict__ ed,
    const int* __restrict__ cnt_g, const int* __restrict__ slot,
    const float* __restrict__ bias, float* __restrict__ gout){
  int lane = threadIdx.x & 63, wave = threadIdx.x >> 6;
  int h = lane >> 5, ln = lane & 31;
  int gd = (blockIdx.x*4 + wave)*2 + h;   // 12000 blocks -> 96000 pairs
  int g = gd / N_, d = gd - g*N_;
  int start = d << 6;
  int deg = min(cnt_g[d], DEGCAP);
  const float* esg = es + (size_t)g*N_;
  float edv = ed[(size_t)g*N_ + d];
  const char* hg = (const char*)(hbuf + (size_t)g*N_*H_);
  unsigned lanoff = ((unsigned)ln) << 2;
  int hbase = h << 5;
  int dm = max(deg, __shfl_xor(deg, 32, 64));   // wave-uniform max degree

  float acc0 = 0.f, acc1 = 0.f;
  if (dm <= 32){
    int sv = 0; float sc = -1e30f;
    if (ln < deg){
      sv = slot[start + ln];
      float e = esg[sv] + edv;
      sc = e > 0.f ? e : 0.2f*e;
    }
    float m = half_max(sc);
    float ex = (ln < deg) ? __expf(sc - m) : 0.f;
    float ssum = half_sum(ex);
    ex *= fastrcp(ssum + 1e-16f);
    unsigned pw = (f2bf_rtn(ex) << 16) | (unsigned)sv;   // alpha(bf16) | src_id
    for (int j0 = 0; j0 < dm; j0 += 8){
      unsigned wv[8]; float aa[8]; unsigned off[8];
      #pragma unroll
      for (int u = 0; u < 8; ++u){
        int j = j0 + u;
        wv[u] = (unsigned)__shfl((int)pw, hbase + j, 64);
        aa[u] = (j < deg) ? uasf(wv[u] & 0xffff0000u) : 0.f;
        off[u] = ((wv[u] & 0xffffu) << 7) + lanoff;
      }
      unsigned hv[8];
      #pragma unroll
      for (int u = 0; u < 8; ++u)
        hv[u] = *(const unsigned*)(hg + off[u]);
      #pragma unroll
      for (int u = 0; u < 8; ++u){
        acc0 = fmaf(aa[u], uasf(hv[u] << 16), acc0);
        acc1 = fmaf(aa[u], uasf(hv[u] & 0xffff0000u), acc1);
      }
    }
  } else {
    // general chunked path (deg > 32): 32-wide chunks per half
    float m = -1e30f;
    for (int base = 0; base < deg; base += 32){
      int i = base + ln;
      if (i < deg){
        int s = slot[start + i];
        float e = esg[s] + edv;
        float t = e > 0.f ? e : 0.2f*e;
        m = fmaxf(m, t);
      }
    }
    m = half_max(m);
    float ssum = 0.f;
    for (int base = 0; base < deg; base += 32){
      int i = base + ln;
      if (i < deg){
        int s = slot[start + i];
        float e = esg[s] + edv;
        float t = e > 0.f ? e : 0.2f*e;
        ssum += __expf(t - m);
      }
    }
    ssum = half_sum(ssum);
    float inv = fastrcp(ssum + 1e-16f);
    for (int base = 0; base < dm; base += 32){
      int i = base + ln;
      int sv = 0; float ex = 0.f;
      if (i < deg){
        sv = slot[start + i];
        float e = esg[sv] + edv;
        float t = e > 0.f ? e : 0.2f*e;
        ex = __expf(t - m) * inv;
      }
      unsigned pw = (f2bf_rtn(ex) << 16) | (unsigned)sv;
      int rem = dm - base; if (rem > 32) rem = 32;
      int myrem = deg - base;
      for (int j0 = 0; j0 < rem; j0 += 8){
        unsigned wv[8]; float aa[8]; unsigned off[8];
        #pragma unroll
        for (int u = 0; u < 8; ++u){
          int j = j0 + u;
          wv[u] = (unsigned)__shfl((int)pw, hbase + j, 64);
          aa[u] = (j < myrem) ? uasf(wv[u] & 0xffff0000u) : 0.f;
          off[u] = ((wv[u] & 0xffffu) << 7) + lanoff;
        }
        unsigned hv[8];
        #pragma unroll
        for (int u = 0; u < 8; ++u)
          hv[u] = *(const unsigned*)(hg + off[u]);
        #pragma unroll
        for (int u = 0; u < 8; ++u){
          acc0 = fmaf(aa[u], uasf(hv[u] << 16), acc0);
          acc1 = fmaf(aa[u], uasf(hv[u] & 0xffff0000u), acc1);
        }
      }
    }
  }
  float2 bv = ((const float2*)bias)[ln];
  float2 o2;
  o2.x = gelu_exact(acc0 + bv.x);
  o2.y = gelu_exact(acc1 + bv.y);
  ((float2*)(gout + (size_t)gd*H_))[ln] = o2;
}

// ---------- LSTM via MFMA + fused LayerNorm/dense epilogue ----------
__global__ __launch_bounds__(256) void lstm_final_kernel(
    const float* __restrict__ xin,   // flat [BN*T, 64]: row = seq*T + t
    const float* __restrict__ Wih,   // [256][64] row-major
    const float* __restrict__ Whh,   // [256][64] row-major
    const float* __restrict__ bih, const float* __restrict__ bhh,
    const float* __restrict__ lng, const float* __restrict__ lnb,
    const float* __restrict__ dW, const float* __restrict__ db,
    const int* __restrict__ flag, void* __restrict__ outv){
  __shared__ __align__(16) unsigned short Hlds[16*LSTM_PAD];
  __shared__ float smH[16][68];      // +4 pad: conflict-light
  int tid = threadIdx.x;
  int lane = tid & 63, wave = tid >> 6;
  int q = lane >> 4, c = lane & 15;
  int s0 = blockIdx.x * 16;

  bf16x8 Bf[4][4];
  #pragma unroll
  for (int g = 0; g < 4; ++g){
    int n = g*64 + wave*16 + c;
    #pragma unroll
    for (int ks = 0; ks < 4; ++ks){
      const float* srcp = (ks < 2) ? (Whh + (size_t)n*64 + ks*32 + q*8)
                                   : (Wih + (size_t)n*64 + (ks-2)*32 + q*8);
      float4 a = ((const float4*)srcp)[0];
      float4 b = ((const float4*)srcp)[1];
      Bf[g][ks] = pack8(a, b);
    }
  }
  float bsum[4];
  #pragma unroll
  for (int g = 0; g < 4; ++g){
    int n = g*64 + wave*16 + c;
    bsum[g] = bih[n] + bhh[n];
  }
  for (int i = tid; i < 16*LSTM_PAD; i += 256) Hlds[i] = 0;
  float cst[4] = {0.f, 0.f, 0.f, 0.f};
  __syncthreads();

  for (int t = 0; t < T_; ++t){
    const float4* xr4 = (const float4*)(xin + ((size_t)(s0 + c)*T_ + t)*64);
    float4 x0 = xr4[q*2],     x1 = xr4[q*2 + 1];
    float4 x2 = xr4[8 + q*2], x3 = xr4[8 + q*2 + 1];
    bf16x8 Ax0 = pack8(x0, x1);
    bf16x8 Ax1 = pack8(x2, x3);
    const bf16x8* hrow = (const bf16x8*)(Hlds + c*LSTM_PAD);
    bf16x8 Ah0 = hrow[q];
    bf16x8 Ah1 = hrow[4 + q];

    f32x4 acc[4];
    #pragma unroll
    for (int g = 0; g < 4; ++g){ acc[g][0]=bsum[g]; acc[g][1]=bsum[g]; acc[g][2]=bsum[g]; acc[g][3]=bsum[g]; }
    #pragma unroll
    for (int g = 0; g < 4; ++g) acc[g] = __builtin_amdgcn_mfma_f32_16x16x32_bf16(Ah0, Bf[g][0], acc[g], 0, 0, 0);
    #pragma unroll
    for (int g = 0; g < 4; ++g) acc[g] = __builtin_amdgcn_mfma_f32_16x16x32_bf16(Ah1, Bf[g][1], acc[g], 0, 0, 0);
    #pragma unroll
    for (int g = 0; g < 4; ++g) acc[g] = __builtin_amdgcn_mfma_f32_16x16x32_bf16(Ax0, Bf[g][2], acc[g], 0, 0, 0);
    #pragma unroll
    for (int g = 0; g < 4; ++g) acc[g] = __builtin_amdgcn_mfma_f32_16x16x32_bf16(Ax1, Bf[g][3], acc[g], 0, 0, 0);

    float hv[4];
    #pragma unroll
    for (int r = 0; r < 4; ++r){
      float zi = acc[0][r], zf = acc[1][r], zg = acc[2][r], zo = acc[3][r];
      cst[r] = sigf(zf)*cst[r] + sigf(zi)*tanhfast(zg);
      hv[r] = sigf(zo)*tanhfast(cst[r]);
    }
    if (t == T_-1){
      #pragma unroll
      for (int r = 0; r < 4; ++r)
        smH[q*4 + r][wave*16 + c] = hv[r];
    } else {
      __syncthreads();
      #pragma unroll
      for (int r = 0; r < 4; ++r)
        Hlds[(q*4 + r)*LSTM_PAD + wave*16 + c] = (unsigned short)f2bf_rtn(hv[r]);
      __syncthreads();
    }
  }
  __syncthreads();

  // fused LayerNorm + dense[64,12]; wave w handles seqs 4w..4w+3
  int isbf = *flag;
  #pragma unroll
  for (int si = 0; si < 4; ++si){
    int s = wave*4 + si;
    float h = smH[s][lane];
    float mu = wave_sum(h) * (1.f/64.f);
    float dev = h - mu;
    float var = wave_sum(dev*dev) * (1.f/64.f);
    float hn = dev * rsqrtf(var + 1e-5f) * lng[lane] + lnb[lane];
    smH[s][lane] = hn;       // wave-internal write->read, in-order LDS
    if (lane < 12){
      float o = db[lane];
      #pragma unroll
      for (int k = 0; k < 64; ++k) o = fmaf(smH[s][k], dW[k*12 + lane], o);
      size_t oi = (size_t)(s0 + s)*12 + lane;
      if (isbf) ((unsigned short*)outv)[oi] = (unsigned short)f2bf_rtn(o);
      else      ((float*)outv)[oi] = o;
    }
  }
}

extern "C" void kernel_launch(void* const* d_in, const int* in_sizes, int n_in,
                              void* d_out, int out_size, void* d_ws, size_t ws_size,
                              hipStream_t stream) {
  const int* esrc = (const int*)d_in[1];
  const int* edst = (const int*)d_in[2];

  static const int sizes[18] = {512, 64, 4096, 64, 64, 64, 4096, 64, 64, 64,
                                16384, 16384, 256, 256, 64, 64, 768, 12};
  static const int srcidx[18] = {3, 4, 5, 6, 7, 8, 9, 10, 11, 12,
                                 13, 14, 15, 16, 17, 18, 19, 20};
  ConvArgs ca;
  {
    int acc = 0;
    for (int i = 0; i < 18; ++i){ ca.src[i] = d_in[srcidx[i]]; ca.off[i] = acc; acc += sizes[i]; }
    ca.off[18] = acc;   // == NPARAM_
  }

  float* P     = (float*)d_ws;               // [NPARAM_PAD_]
  float* bufA  = P + NPARAM_PAD_;            // gout1 -> g2out
  float* bufB  = bufA + (size_t)GNH_;        // hbuf(bf16)
  float* esb   = bufB + (size_t)GNH_;
  float* edb   = esb  + (size_t)G_*N_;
  int*   cnt_g = (int*)(edb + (size_t)G_*N_);// [N_]
  int*   slot  = cnt_g + N_;                 // [N_*64]
  int*   flag  = slot + N_*DEGCAP;           // [1]
  float* wcb   = (float*)(flag + 1);         // Wc[512] + bc[64]
  unsigned short* hbuf = (unsigned short*)bufB;

  const float* pg1b = P + 4672;
  const float* pg1as= P + 4736;
  const float* pg1ad= P + 4800;
  const float* pg2W = P + 4864;
  const float* pg2b = P + 8960;
  const float* pg2as= P + 9024;
  const float* pg2ad= P + 9088;
  const float* pWih = P + 9152;
  const float* pWhh = P + 25536;
  const float* pbih = P + 41920;
  const float* pbhh = P + 42176;
  const float* plng = P + 42432;
  const float* plnb = P + 42496;
  const float* pdW  = P + 42560;
  const float* pdb  = P + 43328;

  prep_kernel<<<172, 256, 0, stream>>>(ca, (const unsigned*)d_in[0],
                                       P, flag, cnt_g, wcb, wcb + 512);

  gat_h1_fused_kernel<<<750, 256, 0, stream>>>(d_in[0], flag, esrc, edst, cnt_g, slot,
                                               wcb, wcb + 512, pg1as, pg1ad, hbuf, esb, edb);
  gat_agg_kernel<<<12000, 256, 0, stream>>>(hbuf, esb, edb, cnt_g, slot, pg1b, bufA);

  gat_h2_mfma_kernel<<<750, 256, 0, stream>>>(bufA, pg2W, pg2as, pg2ad, hbuf, esb, edb);
  gat_agg_kernel<<<12000, 256, 0, stream>>>(hbuf, esb, edb, cnt_g, slot, pg2b, bufA);

  lstm_final_kernel<<<250, 256, 0, stream>>>(bufA, pWih, pWhh, pbih, pbhh,
                                             plng, plnb, pdW, pdb, flag, d_out);
}

// Round 12
// 233.201 us; speedup vs baseline: 1.3842x; 1.0596x over previous
//
#include <hip/hip_runtime.h>
#include <hip/hip_bf16.h>
#include <math.h>

#define B_   2
#define N_   2000
#define T_   24
#define NX_  8
#define H_   64
#define G_   (B_*T_)        // 48 graphs
#define E_   32000
#define BN_  (B_*N_)        // 4000 sequences
#define TH_  (T_*H_)        // 1536
#define NTH_ (N_*T_*H_)     // 3072000
#define GNH_ (G_*N_*H_)     // 6144000
#define NPARAM_ 43340       // canonical fp32 param elements (x excluded)
#define NPARAM_PAD_ 43392
#define LSTM_PAD 72         // padded H-row (bf16 elems): 144B stride, 16B aligned, <=2-way banks
#define DEGCAP 64           // slot capacity per dst node (max binomial deg ~35)

using bf16 = __hip_bfloat16;
typedef short bf16x8 __attribute__((ext_vector_type(8)));
typedef float f32x4  __attribute__((ext_vector_type(4)));

__device__ __forceinline__ float uasf(unsigned u){ return __uint_as_float(u); }
__device__ __forceinline__ float wave_sum(float v){
  #pragma unroll
  for (int o = 32; o > 0; o >>= 1) v += __shfl_xor(v, o, 64);
  return v;
}
__device__ __forceinline__ float fastrcp(float x){ return __builtin_amdgcn_rcpf(x); }
__device__ __forceinline__ float sigf(float x){ return fastrcp(1.f + __expf(-x)); }
__device__ __forceinline__ float tanhfast(float x){ return 1.f - 2.f*fastrcp(1.f + __expf(2.f*x)); }
__device__ __forceinline__ float gelu_exact(float x){ return 0.5f*x*(1.f + erff(x*0.70710678118654752f)); }
__device__ __forceinline__ unsigned f2bf_rtn(float f){
  unsigned u = __float_as_uint(f);
  u += 0x7fffu + ((u >> 16) & 1u);
  return u >> 16;
}
__device__ __forceinline__ bf16x8 pack8(float4 a, float4 b){
  bf16x8 v;
  v[0]=(short)f2bf_rtn(a.x); v[1]=(short)f2bf_rtn(a.y);
  v[2]=(short)f2bf_rtn(a.z); v[3]=(short)f2bf_rtn(a.w);
  v[4]=(short)f2bf_rtn(b.x); v[5]=(short)f2bf_rtn(b.y);
  v[6]=(short)f2bf_rtn(b.z); v[7]=(short)f2bf_rtn(b.w);
  return v;
}

// ---------- prep: dtype detect + param convert + cnt zero + Wc fold, ONE dispatch ----------
struct ConvArgs {
  const void* src[18];
  int off[19];
};
__global__ __launch_bounds__(256) void prep_kernel(
    ConvArgs a, const unsigned* __restrict__ xw,
    float* __restrict__ dst, int* __restrict__ flag,
    int* __restrict__ cnt_g,
    float* __restrict__ wc, float* __restrict__ bc){
  __shared__ int scnt;
  int tid = threadIdx.x;
  if (tid == 0) scnt = 0;
  __syncthreads();
  int c = 0;
  for (int i = tid; i < 4096; i += 256){
    unsigned e = (xw[i] >> 7) & 0xffu;
    if (e >= 100u && e <= 140u) c++;
  }
  atomicAdd(&scnt, c);
  __syncthreads();
  int isbf = (scnt > 3276) ? 1 : 0;
  int bid = blockIdx.x;

  if (bid < 170){
    if (bid == 0 && tid == 0) *flag = isbf;
    int i = bid*256 + tid;
    if (i < NPARAM_){
      int seg = 0;
      while (i >= a.off[seg+1]) seg++;
      int j = i - a.off[seg];
      float v;
      if (isbf) v = uasf(((unsigned)((const unsigned short*)a.src[seg])[j]) << 16);
      else      v = ((const float*)a.src[seg])[j];
      dst[i] = v;
    }
  } else if (bid == 170){
    for (int i = tid; i < N_; i += 256) cnt_g[i] = 0;
  } else {
    // bid == 171: Wc = fcW @ g1W, bc = fcb @ g1W (inline dtype conversion)
    const void* pfcW = a.src[0];
    const void* pfcb = a.src[1];
    const void* pg1W = a.src[2];
    #pragma unroll
    for (int half = 0; half < 2; ++half){
      int t2 = half*256 + tid;              // 0..511
      int i = t2 >> 6, n = t2 & 63;
      float s = 0.f;
      #pragma unroll
      for (int k = 0; k < 64; ++k){
        float fa = isbf ? uasf(((unsigned)((const unsigned short*)pfcW)[i*64+k]) << 16)
                        : ((const float*)pfcW)[i*64+k];
        float fb = isbf ? uasf(((unsigned)((const unsigned short*)pg1W)[k*64+n]) << 16)
                        : ((const float*)pg1W)[k*64+n];
        s = fmaf(fa, fb, s);
      }
      wc[i*64 + n] = s;
    }
    if (tid < 64){
      float b = 0.f;
      #pragma unroll
      for (int k = 0; k < 64; ++k){
        float fa = isbf ? uasf(((unsigned)((const unsigned short*)pfcb)[k]) << 16)
                        : ((const float*)pfcb)[k];
        float fb = isbf ? uasf(((unsigned)((const unsigned short*)pg1W)[k*64+tid]) << 16)
                        : ((const float*)pg1W)[k*64+tid];
        b = fmaf(fa, fb, b);
      }
      bc[tid] = b;
    }
  }
}

// ---------- GAT1 fused: edge-table build (blocks 0..124) + h = x @ Wc + bc via MFMA ----------
__global__ __launch_bounds__(256) void gat_h1_fused_kernel(
    const void* __restrict__ xraw, const int* __restrict__ flag,
    const int* __restrict__ esrc, const int* __restrict__ edst,
    int* __restrict__ cnt_g, int* __restrict__ slot,
    const float* __restrict__ wc, const float* __restrict__ bc,
    const float* __restrict__ asrc, const float* __restrict__ adst,
    unsigned short* __restrict__ hbuf, float* __restrict__ es, float* __restrict__ ed){
  // edge build: 125 blocks x 256 edges, fully parallel, overlapped with MFMA blocks
  if (blockIdx.x < 125){
    int e = blockIdx.x*256 + threadIdx.x;      // exactly covers E_=32000
    int d = edst[e];
    int pos = atomicAdd(&cnt_g[d], 1);
    if (pos < DEGCAP) slot[(d << 6) + pos] = esrc[e];
  }
  int lane = threadIdx.x & 63, wave = threadIdx.x >> 6;
  int q = lane >> 4, c = lane & 15;
  int isbf = *flag;
  bf16x8 Bf[4];                       // B[n=c][k=q*8+j]; only q==0 rows of Wc nonzero
  #pragma unroll
  for (int nt = 0; nt < 4; ++nt){
    bf16x8 v;
    #pragma unroll
    for (int j = 0; j < 8; ++j)
      v[j] = (q == 0) ? (short)f2bf_rtn(wc[j*64 + nt*16 + c]) : (short)0;
    Bf[nt] = v;
  }
  float bcv[4];
  #pragma unroll
  for (int nt = 0; nt < 4; ++nt) bcv[nt] = bc[nt*16 + c];
  float aS[4], aD[4];
  #pragma unroll
  for (int nt = 0; nt < 4; ++nt){ aS[nt] = asrc[nt*16+c]; aD[nt] = adst[nt*16+c]; }

  int w = blockIdx.x*4 + wave;        // 750*4 = 3000 waves, 2 tiles each
  #pragma unroll
  for (int it = 0; it < 2; ++it){
    int tile = w*2 + it;
    int p0 = tile*16;
    int g  = p0 / N_, n0 = p0 - g*N_;
    int bb = g / T_,  tt = g - bb*T_;
    bf16x8 A0;
    #pragma unroll
    for (int j = 0; j < 8; ++j) A0[j] = 0;
    if (q == 0){
      size_t rowelt = ((size_t)(bb*N_ + n0 + c)*T_ + tt)*NX_;
      if (isbf){
        A0 = *(const bf16x8*)((const unsigned short*)xraw + rowelt);
      } else {
        const float4* xr4 = (const float4*)((const float*)xraw + rowelt);
        A0 = pack8(xr4[0], xr4[1]);
      }
    }
    f32x4 acc[4];
    #pragma unroll
    for (int nt = 0; nt < 4; ++nt){ acc[nt][0]=bcv[nt]; acc[nt][1]=bcv[nt]; acc[nt][2]=bcv[nt]; acc[nt][3]=bcv[nt]; }
    #pragma unroll
    for (int nt = 0; nt < 4; ++nt) acc[nt] = __builtin_amdgcn_mfma_f32_16x16x32_bf16(A0, Bf[nt], acc[nt], 0, 0, 0);

    #pragma unroll
    for (int nt = 0; nt < 4; ++nt){
      #pragma unroll
      for (int r = 0; r < 4; ++r)
        hbuf[(size_t)(p0 + q*4 + r)*H_ + nt*16 + c] = (unsigned short)f2bf_rtn(acc[nt][r]);
    }
    #pragma unroll
    for (int r = 0; r < 4; ++r){
      float e1 = acc[0][r]*aS[0] + acc[1][r]*aS[1] + acc[2][r]*aS[2] + acc[3][r]*aS[3];
      float e2 = acc[0][r]*aD[0] + acc[1][r]*aD[1] + acc[2][r]*aD[2] + acc[3][r]*aD[3];
      #pragma unroll
      for (int o = 8; o > 0; o >>= 1){
        e1 += __shfl_xor(e1, o, 64);
        e2 += __shfl_xor(e2, o, 64);
      }
      if (c == 0){
        es[p0 + q*4 + r] = e1;
        ed[p0 + q*4 + r] = e2;
      }
    }
  }
}

// ---------- GAT2 h = gout1 @ W via MFMA (scrambled raw-reshape reads) ----------
__global__ __launch_bounds__(256) void gat_h2_mfma_kernel(
    const float* __restrict__ xin, const float* __restrict__ W,
    const float* __restrict__ asrc, const float* __restrict__ adst,
    unsigned short* __restrict__ hbuf, float* __restrict__ es, float* __restrict__ ed){
  int lane = threadIdx.x & 63, wave = threadIdx.x >> 6;
  int q = lane >> 4, c = lane & 15;
  bf16x8 Bf[4][2];
  #pragma unroll
  for (int nt = 0; nt < 4; ++nt){
    #pragma unroll
    for (int ks = 0; ks < 2; ++ks){
      bf16x8 v;
      #pragma unroll
      for (int j = 0; j < 8; ++j)
        v[j] = (short)f2bf_rtn(W[(ks*32 + q*8 + j)*H_ + nt*16 + c]);
      Bf[nt][ks] = v;
    }
  }
  float aS[4], aD[4];
  #pragma unroll
  for (int nt = 0; nt < 4; ++nt){ aS[nt] = asrc[nt*16+c]; aD[nt] = adst[nt*16+c]; }

  int w = blockIdx.x*4 + wave;
  #pragma unroll
  for (int it = 0; it < 2; ++it){
    int tile = w*2 + it;
    int p0 = tile*16;
    int p  = p0 + c;
    int g = p / N_, n = p - g*N_;
    int bb = g / T_, t = g - bb*T_;
    const float4* xr4 = (const float4*)(xin + (size_t)bb*NTH_ + (size_t)n*TH_ + (size_t)t*H_);
    float4 x0 = xr4[q*2],     x1 = xr4[q*2 + 1];
    float4 x2 = xr4[8 + q*2], x3 = xr4[8 + q*2 + 1];
    bf16x8 A0 = pack8(x0, x1);
    bf16x8 A1 = pack8(x2, x3);

    f32x4 acc[4];
    #pragma unroll
    for (int nt = 0; nt < 4; ++nt){ acc[nt][0]=0.f; acc[nt][1]=0.f; acc[nt][2]=0.f; acc[nt][3]=0.f; }
    #pragma unroll
    for (int nt = 0; nt < 4; ++nt) acc[nt] = __builtin_amdgcn_mfma_f32_16x16x32_bf16(A0, Bf[nt][0], acc[nt], 0, 0, 0);
    #pragma unroll
    for (int nt = 0; nt < 4; ++nt) acc[nt] = __builtin_amdgcn_mfma_f32_16x16x32_bf16(A1, Bf[nt][1], acc[nt], 0, 0, 0);

    #pragma unroll
    for (int nt = 0; nt < 4; ++nt){
      #pragma unroll
      for (int r = 0; r < 4; ++r)
        hbuf[(size_t)(p0 + q*4 + r)*H_ + nt*16 + c] = (unsigned short)f2bf_rtn(acc[nt][r]);
    }
    #pragma unroll
    for (int r = 0; r < 4; ++r){
      float e1 = acc[0][r]*aS[0] + acc[1][r]*aS[1] + acc[2][r]*aS[2] + acc[3][r]*aS[3];
      float e2 = acc[0][r]*aD[0] + acc[1][r]*aD[1] + acc[2][r]*aD[2] + acc[3][r]*aD[3];
      #pragma unroll
      for (int o = 8; o > 0; o >>= 1){
        e1 += __shfl_xor(e1, o, 64);
        e2 += __shfl_xor(e2, o, 64);
      }
      if (c == 0){
        es[p0 + q*4 + r] = e1;
        ed[p0 + q*4 + r] = e2;
      }
    }
  }
}

// ---------- GAT aggregate: 4 (g,d) per wave, 16 lanes each, 4 chan/lane uint2 gathers ----------
__global__ __launch_bounds__(256) void gat_agg_kernel(
    const unsigned short* __restrict__ hbuf, const float* __restrict__ es, const float* __restrict__ ed,
    const int* __restrict__ cnt_g, const int* __restrict__ slot,
    const float* __restrict__ bias, float* __restrict__ gout){
  int lane = threadIdx.x & 63, wave = threadIdx.x >> 6;
  int qd = lane >> 4, ln = lane & 15;
  int gd = (blockIdx.x*4 + wave)*4 + qd;   // 6000 blocks -> 96000 pairs
  int g = gd / N_, d = gd - g*N_;
  int start = d << 6;
  int deg = min(cnt_g[d], DEGCAP);
  const float* esg = es + (size_t)g*N_;
  float edv = ed[(size_t)g*N_ + d];
  const char* hg = (const char*)(hbuf + (size_t)g*N_*H_);
  unsigned lanoff = ((unsigned)ln) << 3;   // 8 B per lane = 4 bf16 channels
  int hbase = qd << 4;
  int dm = deg;                             // wave-uniform max degree over 4 groups
  dm = max(dm, __shfl_xor(dm, 16, 64));
  dm = max(dm, __shfl_xor(dm, 32, 64));
  int NC = (dm + 15) >> 4;                  // chunks of 16, <=4

  // pass 1: load slot ids + scores into registers (all loads independent)
  int svk[4]; float sck[4];
  #pragma unroll
  for (int k = 0; k < 4; ++k){ svk[k] = 0; sck[k] = -1e30f; }
  #pragma unroll
  for (int k = 0; k < 4; ++k){
    int i = k*16 + ln;
    if (k < NC && i < deg) svk[k] = slot[start + i];
  }
  #pragma unroll
  for (int k = 0; k < 4; ++k){
    int i = k*16 + ln;
    if (k < NC && i < deg){
      float e = esg[svk[k]] + edv;
      sck[k] = e > 0.f ? e : 0.2f*e;
    }
  }
  float m = fmaxf(fmaxf(sck[0], sck[1]), fmaxf(sck[2], sck[3]));
  #pragma unroll
  for (int o = 8; o > 0; o >>= 1) m = fmaxf(m, __shfl_xor(m, o, 64));
  // pass 2: register-only exp + sum
  float exk[4]; float ssum = 0.f;
  #pragma unroll
  for (int k = 0; k < 4; ++k){
    int i = k*16 + ln;
    float e = (k < NC && i < deg) ? __expf(sck[k] - m) : 0.f;
    exk[k] = e; ssum += e;
  }
  #pragma unroll
  for (int o = 8; o > 0; o >>= 1) ssum += __shfl_xor(ssum, o, 64);
  float inv = fastrcp(ssum + 1e-16f);
  unsigned pwk[4];
  #pragma unroll
  for (int k = 0; k < 4; ++k)
    pwk[k] = (f2bf_rtn(exk[k]*inv) << 16) | (unsigned)svk[k];

  // pass 3: gather h rows (uint2 = 4 channels) with shfl-broadcast ids
  float a0 = 0.f, a1 = 0.f, a2 = 0.f, a3 = 0.f;
  for (int k = 0; k < NC; ++k){
    unsigned pw = pwk[k];
    int myrem = deg - k*16;                 // per-group remaining (predicate only)
    int remw = dm - k*16; if (remw > 16) remw = 16;   // wave-uniform trip
    for (int j0 = 0; j0 < remw; j0 += 8){
      unsigned wv[8]; float aa[8]; unsigned off[8];
      #pragma unroll
      for (int u = 0; u < 8; ++u){
        int j = j0 + u;
        wv[u] = (unsigned)__shfl((int)pw, hbase + j, 64);
        aa[u] = (j < myrem) ? uasf(wv[u] & 0xffff0000u) : 0.f;
        off[u] = ((wv[u] & 0xffffu) << 7) + lanoff;
      }
      uint2 hv[8];
      #pragma unroll
      for (int u = 0; u < 8; ++u)
        hv[u] = *(const uint2*)(hg + off[u]);
      #pragma unroll
      for (int u = 0; u < 8; ++u){
        a0 = fmaf(aa[u], uasf(hv[u].x << 16), a0);
        a1 = fmaf(aa[u], uasf(hv[u].x & 0xffff0000u), a1);
        a2 = fmaf(aa[u], uasf(hv[u].y << 16), a2);
        a3 = fmaf(aa[u], uasf(hv[u].y & 0xffff0000u), a3);
      }
    }
  }
  float4 bv = ((const float4*)bias)[ln];
  float4 o4;
  o4.x = gelu_exact(a0 + bv.x);
  o4.y = gelu_exact(a1 + bv.y);
  o4.z = gelu_exact(a2 + bv.z);
  o4.w = gelu_exact(a3 + bv.w);
  ((float4*)(gout + (size_t)gd*H_))[ln] = o4;
}

// ---------- LSTM via MFMA + fused LayerNorm/dense epilogue ----------
__global__ __launch_bounds__(256) void lstm_final_kernel(
    const float* __restrict__ xin,   // flat [BN*T, 64]: row = seq*T + t
    const float* __restrict__ Wih,   // [256][64] row-major
    const float* __restrict__ Whh,   // [256][64] row-major
    const float* __restrict__ bih, const float* __restrict__ bhh,
    const float* __restrict__ lng, const float* __restrict__ lnb,
    const float* __restrict__ dW, const float* __restrict__ db,
    const int* __restrict__ flag, void* __restrict__ outv){
  __shared__ __align__(16) unsigned short Hlds[16*LSTM_PAD];
  __shared__ float smH[16][68];      // +4 pad: conflict-light
  int tid = threadIdx.x;
  int lane = tid & 63, wave = tid >> 6;
  int q = lane >> 4, c = lane & 15;
  int s0 = blockIdx.x * 16;

  bf16x8 Bf[4][4];
  #pragma unroll
  for (int g = 0; g < 4; ++g){
    int n = g*64 + wave*16 + c;
    #pragma unroll
    for (int ks = 0; ks < 4; ++ks){
      const float* srcp = (ks < 2) ? (Whh + (size_t)n*64 + ks*32 + q*8)
                                   : (Wih + (size_t)n*64 + (ks-2)*32 + q*8);
      float4 a = ((const float4*)srcp)[0];
      float4 b = ((const float4*)srcp)[1];
      Bf[g][ks] = pack8(a, b);
    }
  }
  float bsum[4];
  #pragma unroll
  for (int g = 0; g < 4; ++g){
    int n = g*64 + wave*16 + c;
    bsum[g] = bih[n] + bhh[n];
  }
  for (int i = tid; i < 16*LSTM_PAD; i += 256) Hlds[i] = 0;
  float cst[4] = {0.f, 0.f, 0.f, 0.f};
  __syncthreads();

  for (int t = 0; t < T_; ++t){
    const float4* xr4 = (const float4*)(xin + ((size_t)(s0 + c)*T_ + t)*64);
    float4 x0 = xr4[q*2],     x1 = xr4[q*2 + 1];
    float4 x2 = xr4[8 + q*2], x3 = xr4[8 + q*2 + 1];
    bf16x8 Ax0 = pack8(x0, x1);
    bf16x8 Ax1 = pack8(x2, x3);
    const bf16x8* hrow = (const bf16x8*)(Hlds + c*LSTM_PAD);
    bf16x8 Ah0 = hrow[q];
    bf16x8 Ah1 = hrow[4 + q];

    f32x4 acc[4];
    #pragma unroll
    for (int g = 0; g < 4; ++g){ acc[g][0]=bsum[g]; acc[g][1]=bsum[g]; acc[g][2]=bsum[g]; acc[g][3]=bsum[g]; }
    #pragma unroll
    for (int g = 0; g < 4; ++g) acc[g] = __builtin_amdgcn_mfma_f32_16x16x32_bf16(Ah0, Bf[g][0], acc[g], 0, 0, 0);
    #pragma unroll
    for (int g = 0; g < 4; ++g) acc[g] = __builtin_amdgcn_mfma_f32_16x16x32_bf16(Ah1, Bf[g][1], acc[g], 0, 0, 0);
    #pragma unroll
    for (int g = 0; g < 4; ++g) acc[g] = __builtin_amdgcn_mfma_f32_16x16x32_bf16(Ax0, Bf[g][2], acc[g], 0, 0, 0);
    #pragma unroll
    for (int g = 0; g < 4; ++g) acc[g] = __builtin_amdgcn_mfma_f32_16x16x32_bf16(Ax1, Bf[g][3], acc[g], 0, 0, 0);

    float hv[4];
    #pragma unroll
    for (int r = 0; r < 4; ++r){
      float zi = acc[0][r], zf = acc[1][r], zg = acc[2][r], zo = acc[3][r];
      cst[r] = sigf(zf)*cst[r] + sigf(zi)*tanhfast(zg);
      hv[r] = sigf(zo)*tanhfast(cst[r]);
    }
    if (t == T_-1){
      #pragma unroll
      for (int r = 0; r < 4; ++r)
        smH[q*4 + r][wave*16 + c] = hv[r];
    } else {
      __syncthreads();
      #pragma unroll
      for (int r = 0; r < 4; ++r)
        Hlds[(q*4 + r)*LSTM_PAD + wave*16 + c] = (unsigned short)f2bf_rtn(hv[r]);
      __syncthreads();
    }
  }
  __syncthreads();

  // fused LayerNorm + dense[64,12]; wave w handles seqs 4w..4w+3
  int isbf = *flag;
  #pragma unroll
  for (int si = 0; si < 4; ++si){
    int s = wave*4 + si;
    float h = smH[s][lane];
    float mu = wave_sum(h) * (1.f/64.f);
    float dev = h - mu;
    float var = wave_sum(dev*dev) * (1.f/64.f);
    float hn = dev * rsqrtf(var + 1e-5f) * lng[lane] + lnb[lane];
    smH[s][lane] = hn;       // wave-internal write->read, in-order LDS
    if (lane < 12){
      float o = db[lane];
      #pragma unroll
      for (int k = 0; k < 64; ++k) o = fmaf(smH[s][k], dW[k*12 + lane], o);
      size_t oi = (size_t)(s0 + s)*12 + lane;
      if (isbf) ((unsigned short*)outv)[oi] = (unsigned short)f2bf_rtn(o);
      else      ((float*)outv)[oi] = o;
    }
  }
}

extern "C" void kernel_launch(void* const* d_in, const int* in_sizes, int n_in,
                              void* d_out, int out_size, void* d_ws, size_t ws_size,
                              hipStream_t stream) {
  const int* esrc = (const int*)d_in[1];
  const int* edst = (const int*)d_in[2];

  static const int sizes[18] = {512, 64, 4096, 64, 64, 64, 4096, 64, 64, 64,
                                16384, 16384, 256, 256, 64, 64, 768, 12};
  static const int srcidx[18] = {3, 4, 5, 6, 7, 8, 9, 10, 11, 12,
                                 13, 14, 15, 16, 17, 18, 19, 20};
  ConvArgs ca;
  {
    int acc = 0;
    for (int i = 0; i < 18; ++i){ ca.src[i] = d_in[srcidx[i]]; ca.off[i] = acc; acc += sizes[i]; }
    ca.off[18] = acc;   // == NPARAM_
  }

  float* P     = (float*)d_ws;               // [NPARAM_PAD_]
  float* bufA  = P + NPARAM_PAD_;            // gout1 -> g2out
  float* bufB  = bufA + (size_t)GNH_;        // hbuf(bf16)
  float* esb   = bufB + (size_t)GNH_;
  float* edb   = esb  + (size_t)G_*N_;
  int*   cnt_g = (int*)(edb + (size_t)G_*N_);// [N_]
  int*   slot  = cnt_g + N_;                 // [N_*64]
  int*   flag  = slot + N_*DEGCAP;           // [1]
  float* wcb   = (float*)(flag + 1);         // Wc[512] + bc[64]
  unsigned short* hbuf = (unsigned short*)bufB;

  const float* pg1b = P + 4672;
  const float* pg1as= P + 4736;
  const float* pg1ad= P + 4800;
  const float* pg2W = P + 4864;
  const float* pg2b = P + 8960;
  const float* pg2as= P + 9024;
  const float* pg2ad= P + 9088;
  const float* pWih = P + 9152;
  const float* pWhh = P + 25536;
  const float* pbih = P + 41920;
  const float* pbhh = P + 42176;
  const float* plng = P + 42432;
  const float* plnb = P + 42496;
  const float* pdW  = P + 42560;
  const float* pdb  = P + 43328;

  prep_kernel<<<172, 256, 0, stream>>>(ca, (const unsigned*)d_in[0],
                                       P, flag, cnt_g, wcb, wcb + 512);

  gat_h1_fused_kernel<<<750, 256, 0, stream>>>(d_in[0], flag, esrc, edst, cnt_g, slot,
                                               wcb, wcb + 512, pg1as, pg1ad, hbuf, esb, edb);
  gat_agg_kernel<<<6000, 256, 0, stream>>>(hbuf, esb, edb, cnt_g, slot, pg1b, bufA);

  gat_h2_mfma_kernel<<<750, 256, 0, stream>>>(bufA, pg2W, pg2as, pg2ad, hbuf, esb, edb);
  gat_agg_kernel<<<6000, 256, 0, stream>>>(hbuf, esb, edb, cnt_g, slot, pg2b, bufA);

  lstm_final_kernel<<<250, 256, 0, stream>>>(bufA, pWih, pWhh, pbih, pbhh,
                                             plng, plnb, pdW, pdb, flag, d_out);
}

// Round 13
// 226.566 us; speedup vs baseline: 1.4248x; 1.0293x over previous
//
#include <hip/hip_runtime.h>
#include <hip/hip_bf16.h>
#include <math.h>

#define B_   2
#define N_   2000
#define T_   24
#define NX_  8
#define H_   64
#define G_   (B_*T_)        // 48 graphs
#define E_   32000
#define BN_  (B_*N_)        // 4000 sequences
#define TH_  (T_*H_)        // 1536
#define NTH_ (N_*T_*H_)     // 3072000
#define GNH_ (G_*N_*H_)     // 6144000
#define NPARAM_ 43340       // canonical fp32 param elements (x excluded)
#define NPARAM_PAD_ 43392
#define LSTM_PAD 72         // padded H-row (bf16 elems): 144B stride, 16B aligned, <=2-way banks
#define DEGCAP 64           // slot capacity per dst node (max binomial deg ~35)

using bf16 = __hip_bfloat16;
typedef short bf16x8 __attribute__((ext_vector_type(8)));
typedef float f32x4  __attribute__((ext_vector_type(4)));

__device__ __forceinline__ float uasf(unsigned u){ return __uint_as_float(u); }
__device__ __forceinline__ float wave_sum(float v){
  #pragma unroll
  for (int o = 32; o > 0; o >>= 1) v += __shfl_xor(v, o, 64);
  return v;
}
__device__ __forceinline__ float fastrcp(float x){ return __builtin_amdgcn_rcpf(x); }
__device__ __forceinline__ float sigf(float x){ return fastrcp(1.f + __expf(-x)); }
__device__ __forceinline__ float tanhfast(float x){ return 1.f - 2.f*fastrcp(1.f + __expf(2.f*x)); }
__device__ __forceinline__ float gelu_exact(float x){ return 0.5f*x*(1.f + erff(x*0.70710678118654752f)); }
__device__ __forceinline__ unsigned f2bf_rtn(float f){
  unsigned u = __float_as_uint(f);
  u += 0x7fffu + ((u >> 16) & 1u);
  return u >> 16;
}
__device__ __forceinline__ bf16x8 pack8(float4 a, float4 b){
  bf16x8 v;
  v[0]=(short)f2bf_rtn(a.x); v[1]=(short)f2bf_rtn(a.y);
  v[2]=(short)f2bf_rtn(a.z); v[3]=(short)f2bf_rtn(a.w);
  v[4]=(short)f2bf_rtn(b.x); v[5]=(short)f2bf_rtn(b.y);
  v[6]=(short)f2bf_rtn(b.z); v[7]=(short)f2bf_rtn(b.w);
  return v;
}

// ---------- prep: dtype detect + param convert + cnt zero + Wc fold, ONE dispatch ----------
struct ConvArgs {
  const void* src[18];
  int off[19];
};
__global__ __launch_bounds__(256) void prep_kernel(
    ConvArgs a, const unsigned* __restrict__ xw,
    float* __restrict__ dst, int* __restrict__ flag,
    int* __restrict__ cnt_g,
    float* __restrict__ wc, float* __restrict__ bc){
  __shared__ int scnt;
  int tid = threadIdx.x;
  if (tid == 0) scnt = 0;
  __syncthreads();
  int c = 0;
  for (int i = tid; i < 4096; i += 256){
    unsigned e = (xw[i] >> 7) & 0xffu;
    if (e >= 100u && e <= 140u) c++;
  }
  atomicAdd(&scnt, c);
  __syncthreads();
  int isbf = (scnt > 3276) ? 1 : 0;
  int bid = blockIdx.x;

  if (bid < 170){
    if (bid == 0 && tid == 0) *flag = isbf;
    int i = bid*256 + tid;
    if (i < NPARAM_){
      int seg = 0;
      while (i >= a.off[seg+1]) seg++;
      int j = i - a.off[seg];
      float v;
      if (isbf) v = uasf(((unsigned)((const unsigned short*)a.src[seg])[j]) << 16);
      else      v = ((const float*)a.src[seg])[j];
      dst[i] = v;
    }
  } else if (bid == 170){
    for (int i = tid; i < N_; i += 256) cnt_g[i] = 0;
  } else {
    // bid == 171: Wc = fcW @ g1W, bc = fcb @ g1W (inline dtype conversion)
    const void* pfcW = a.src[0];
    const void* pfcb = a.src[1];
    const void* pg1W = a.src[2];
    #pragma unroll
    for (int half = 0; half < 2; ++half){
      int t2 = half*256 + tid;              // 0..511
      int i = t2 >> 6, n = t2 & 63;
      float s = 0.f;
      #pragma unroll
      for (int k = 0; k < 64; ++k){
        float fa = isbf ? uasf(((unsigned)((const unsigned short*)pfcW)[i*64+k]) << 16)
                        : ((const float*)pfcW)[i*64+k];
        float fb = isbf ? uasf(((unsigned)((const unsigned short*)pg1W)[k*64+n]) << 16)
                        : ((const float*)pg1W)[k*64+n];
        s = fmaf(fa, fb, s);
      }
      wc[i*64 + n] = s;
    }
    if (tid < 64){
      float b = 0.f;
      #pragma unroll
      for (int k = 0; k < 64; ++k){
        float fa = isbf ? uasf(((unsigned)((const unsigned short*)pfcb)[k]) << 16)
                        : ((const float*)pfcb)[k];
        float fb = isbf ? uasf(((unsigned)((const unsigned short*)pg1W)[k*64+tid]) << 16)
                        : ((const float*)pg1W)[k*64+tid];
        b = fmaf(fa, fb, b);
      }
      bc[tid] = b;
    }
  }
}

// ---------- GAT1 fused: edge-table build (blocks 0..124) + h = x @ Wc + bc via MFMA ----------
__global__ __launch_bounds__(256) void gat_h1_fused_kernel(
    const void* __restrict__ xraw, const int* __restrict__ flag,
    const int* __restrict__ esrc, const int* __restrict__ edst,
    int* __restrict__ cnt_g, int* __restrict__ slot,
    const float* __restrict__ wc, const float* __restrict__ bc,
    const float* __restrict__ asrc, const float* __restrict__ adst,
    unsigned short* __restrict__ hbuf, float* __restrict__ es, float* __restrict__ ed){
  // edge build: 125 blocks x 256 edges, fully parallel, overlapped with MFMA blocks
  if (blockIdx.x < 125){
    int e = blockIdx.x*256 + threadIdx.x;      // exactly covers E_=32000
    int d = edst[e];
    int pos = atomicAdd(&cnt_g[d], 1);
    if (pos < DEGCAP) slot[(d << 6) + pos] = esrc[e];
  }
  int lane = threadIdx.x & 63, wave = threadIdx.x >> 6;
  int q = lane >> 4, c = lane & 15;
  int isbf = *flag;
  bf16x8 Bf[4];                       // B[n=c][k=q*8+j]; only q==0 rows of Wc nonzero
  #pragma unroll
  for (int nt = 0; nt < 4; ++nt){
    bf16x8 v;
    #pragma unroll
    for (int j = 0; j < 8; ++j)
      v[j] = (q == 0) ? (short)f2bf_rtn(wc[j*64 + nt*16 + c]) : (short)0;
    Bf[nt] = v;
  }
  float bcv[4];
  #pragma unroll
  for (int nt = 0; nt < 4; ++nt) bcv[nt] = bc[nt*16 + c];
  float aS[4], aD[4];
  #pragma unroll
  for (int nt = 0; nt < 4; ++nt){ aS[nt] = asrc[nt*16+c]; aD[nt] = adst[nt*16+c]; }

  int w = blockIdx.x*4 + wave;        // 750*4 = 3000 waves, 2 tiles each
  #pragma unroll
  for (int it = 0; it < 2; ++it){
    int tile = w*2 + it;
    int p0 = tile*16;
    int g  = p0 / N_, n0 = p0 - g*N_;
    int bb = g / T_,  tt = g - bb*T_;
    bf16x8 A0;
    #pragma unroll
    for (int j = 0; j < 8; ++j) A0[j] = 0;
    if (q == 0){
      size_t rowelt = ((size_t)(bb*N_ + n0 + c)*T_ + tt)*NX_;
      if (isbf){
        A0 = *(const bf16x8*)((const unsigned short*)xraw + rowelt);
      } else {
        const float4* xr4 = (const float4*)((const float*)xraw + rowelt);
        A0 = pack8(xr4[0], xr4[1]);
      }
    }
    f32x4 acc[4];
    #pragma unroll
    for (int nt = 0; nt < 4; ++nt){ acc[nt][0]=bcv[nt]; acc[nt][1]=bcv[nt]; acc[nt][2]=bcv[nt]; acc[nt][3]=bcv[nt]; }
    #pragma unroll
    for (int nt = 0; nt < 4; ++nt) acc[nt] = __builtin_amdgcn_mfma_f32_16x16x32_bf16(A0, Bf[nt], acc[nt], 0, 0, 0);

    #pragma unroll
    for (int nt = 0; nt < 4; ++nt){
      #pragma unroll
      for (int r = 0; r < 4; ++r)
        hbuf[(size_t)(p0 + q*4 + r)*H_ + nt*16 + c] = (unsigned short)f2bf_rtn(acc[nt][r]);
    }
    #pragma unroll
    for (int r = 0; r < 4; ++r){
      float e1 = acc[0][r]*aS[0] + acc[1][r]*aS[1] + acc[2][r]*aS[2] + acc[3][r]*aS[3];
      float e2 = acc[0][r]*aD[0] + acc[1][r]*aD[1] + acc[2][r]*aD[2] + acc[3][r]*aD[3];
      #pragma unroll
      for (int o = 8; o > 0; o >>= 1){
        e1 += __shfl_xor(e1, o, 64);
        e2 += __shfl_xor(e2, o, 64);
      }
      if (c == 0){
        es[p0 + q*4 + r] = e1;
        ed[p0 + q*4 + r] = e2;
      }
    }
  }
}

// ---------- GAT2 h = gout1(bf16) @ W via MFMA (scrambled raw-reshape reads) ----------
__global__ __launch_bounds__(256) void gat_h2_mfma_kernel(
    const unsigned short* __restrict__ xinb, const float* __restrict__ W,
    const float* __restrict__ asrc, const float* __restrict__ adst,
    unsigned short* __restrict__ hbuf, float* __restrict__ es, float* __restrict__ ed){
  int lane = threadIdx.x & 63, wave = threadIdx.x >> 6;
  int q = lane >> 4, c = lane & 15;
  bf16x8 Bf[4][2];
  #pragma unroll
  for (int nt = 0; nt < 4; ++nt){
    #pragma unroll
    for (int ks = 0; ks < 2; ++ks){
      bf16x8 v;
      #pragma unroll
      for (int j = 0; j < 8; ++j)
        v[j] = (short)f2bf_rtn(W[(ks*32 + q*8 + j)*H_ + nt*16 + c]);
      Bf[nt][ks] = v;
    }
  }
  float aS[4], aD[4];
  #pragma unroll
  for (int nt = 0; nt < 4; ++nt){ aS[nt] = asrc[nt*16+c]; aD[nt] = adst[nt*16+c]; }

  int w = blockIdx.x*4 + wave;
  #pragma unroll
  for (int it = 0; it < 2; ++it){
    int tile = w*2 + it;
    int p0 = tile*16;
    int p  = p0 + c;
    int g = p / N_, n = p - g*N_;
    int bb = g / T_, t = g - bb*T_;
    const unsigned short* xr = xinb + (size_t)bb*NTH_ + (size_t)n*TH_ + (size_t)t*H_;
    bf16x8 A0 = *(const bf16x8*)(xr + q*8);
    bf16x8 A1 = *(const bf16x8*)(xr + 32 + q*8);

    f32x4 acc[4];
    #pragma unroll
    for (int nt = 0; nt < 4; ++nt){ acc[nt][0]=0.f; acc[nt][1]=0.f; acc[nt][2]=0.f; acc[nt][3]=0.f; }
    #pragma unroll
    for (int nt = 0; nt < 4; ++nt) acc[nt] = __builtin_amdgcn_mfma_f32_16x16x32_bf16(A0, Bf[nt][0], acc[nt], 0, 0, 0);
    #pragma unroll
    for (int nt = 0; nt < 4; ++nt) acc[nt] = __builtin_amdgcn_mfma_f32_16x16x32_bf16(A1, Bf[nt][1], acc[nt], 0, 0, 0);

    #pragma unroll
    for (int nt = 0; nt < 4; ++nt){
      #pragma unroll
      for (int r = 0; r < 4; ++r)
        hbuf[(size_t)(p0 + q*4 + r)*H_ + nt*16 + c] = (unsigned short)f2bf_rtn(acc[nt][r]);
    }
    #pragma unroll
    for (int r = 0; r < 4; ++r){
      float e1 = acc[0][r]*aS[0] + acc[1][r]*aS[1] + acc[2][r]*aS[2] + acc[3][r]*aS[3];
      float e2 = acc[0][r]*aD[0] + acc[1][r]*aD[1] + acc[2][r]*aD[2] + acc[3][r]*aD[3];
      #pragma unroll
      for (int o = 8; o > 0; o >>= 1){
        e1 += __shfl_xor(e1, o, 64);
        e2 += __shfl_xor(e2, o, 64);
      }
      if (c == 0){
        es[p0 + q*4 + r] = e1;
        ed[p0 + q*4 + r] = e2;
      }
    }
  }
}

// ---------- GAT aggregate: 4 (g,d)/wave, 4 chan/lane uint2 gathers, bf16 output ----------
__global__ __launch_bounds__(256) void gat_agg_kernel(
    const unsigned short* __restrict__ hbuf, const float* __restrict__ es, const float* __restrict__ ed,
    const int* __restrict__ cnt_g, const int* __restrict__ slot,
    const float* __restrict__ bias, unsigned short* __restrict__ goutb){
  int lane = threadIdx.x & 63, wave = threadIdx.x >> 6;
  int qd = lane >> 4, ln = lane & 15;
  int gd = (blockIdx.x*4 + wave)*4 + qd;   // 6000 blocks -> 96000 pairs
  int g = gd / N_, d = gd - g*N_;
  int start = d << 6;
  int deg = min(cnt_g[d], DEGCAP);
  const float* esg = es + (size_t)g*N_;
  float edv = ed[(size_t)g*N_ + d];
  const char* hg = (const char*)(hbuf + (size_t)g*N_*H_);
  unsigned lanoff = ((unsigned)ln) << 3;   // 8 B per lane = 4 bf16 channels
  int hbase = qd << 4;
  int dm = deg;                             // wave-uniform max degree over 4 groups
  dm = max(dm, __shfl_xor(dm, 16, 64));
  dm = max(dm, __shfl_xor(dm, 32, 64));
  int NC = (dm + 15) >> 4;                  // chunks of 16, <=4

  // pass 1: load slot ids + scores into registers (all loads independent)
  int svk[4]; float sck[4];
  #pragma unroll
  for (int k = 0; k < 4; ++k){ svk[k] = 0; sck[k] = -1e30f; }
  #pragma unroll
  for (int k = 0; k < 4; ++k){
    int i = k*16 + ln;
    if (k < NC && i < deg) svk[k] = slot[start + i];
  }
  #pragma unroll
  for (int k = 0; k < 4; ++k){
    int i = k*16 + ln;
    if (k < NC && i < deg){
      float e = esg[svk[k]] + edv;
      sck[k] = e > 0.f ? e : 0.2f*e;
    }
  }
  float m = fmaxf(fmaxf(sck[0], sck[1]), fmaxf(sck[2], sck[3]));
  #pragma unroll
  for (int o = 8; o > 0; o >>= 1) m = fmaxf(m, __shfl_xor(m, o, 64));
  // pass 2: register-only exp + sum
  float exk[4]; float ssum = 0.f;
  #pragma unroll
  for (int k = 0; k < 4; ++k){
    int i = k*16 + ln;
    float e = (k < NC && i < deg) ? __expf(sck[k] - m) : 0.f;
    exk[k] = e; ssum += e;
  }
  #pragma unroll
  for (int o = 8; o > 0; o >>= 1) ssum += __shfl_xor(ssum, o, 64);
  float inv = fastrcp(ssum + 1e-16f);
  unsigned pwk[4];
  #pragma unroll
  for (int k = 0; k < 4; ++k)
    pwk[k] = (f2bf_rtn(exk[k]*inv) << 16) | (unsigned)svk[k];

  // pass 3: gather h rows (uint2 = 4 channels) with shfl-broadcast ids
  float a0 = 0.f, a1 = 0.f, a2 = 0.f, a3 = 0.f;
  for (int k = 0; k < NC; ++k){
    unsigned pw = pwk[k];
    int myrem = deg - k*16;                 // per-group remaining (predicate only)
    int remw = dm - k*16; if (remw > 16) remw = 16;   // wave-uniform trip
    for (int j0 = 0; j0 < remw; j0 += 8){
      unsigned wv[8]; float aa[8]; unsigned off[8];
      #pragma unroll
      for (int u = 0; u < 8; ++u){
        int j = j0 + u;
        wv[u] = (unsigned)__shfl((int)pw, hbase + j, 64);
        aa[u] = (j < myrem) ? uasf(wv[u] & 0xffff0000u) : 0.f;
        off[u] = ((wv[u] & 0xffffu) << 7) + lanoff;
      }
      uint2 hv[8];
      #pragma unroll
      for (int u = 0; u < 8; ++u)
        hv[u] = *(const uint2*)(hg + off[u]);
      #pragma unroll
      for (int u = 0; u < 8; ++u){
        a0 = fmaf(aa[u], uasf(hv[u].x << 16), a0);
        a1 = fmaf(aa[u], uasf(hv[u].x & 0xffff0000u), a1);
        a2 = fmaf(aa[u], uasf(hv[u].y << 16), a2);
        a3 = fmaf(aa[u], uasf(hv[u].y & 0xffff0000u), a3);
      }
    }
  }
  float4 bv = ((const float4*)bias)[ln];
  uint2 ov;
  ov.x = f2bf_rtn(gelu_exact(a0 + bv.x)) | (f2bf_rtn(gelu_exact(a1 + bv.y)) << 16);
  ov.y = f2bf_rtn(gelu_exact(a2 + bv.z)) | (f2bf_rtn(gelu_exact(a3 + bv.w)) << 16);
  ((uint2*)(goutb + (size_t)gd*H_))[ln] = ov;
}

// ---------- LSTM via MFMA (bf16 x input, single-barrier dbuf) + fused LN/dense ----------
__global__ __launch_bounds__(256) void lstm_final_kernel(
    const unsigned short* __restrict__ xinb,  // bf16 flat [BN*T, 64]: row = seq*T + t
    const float* __restrict__ Wih,   // [256][64] row-major
    const float* __restrict__ Whh,   // [256][64] row-major
    const float* __restrict__ bih, const float* __restrict__ bhh,
    const float* __restrict__ lng, const float* __restrict__ lnb,
    const float* __restrict__ dW, const float* __restrict__ db,
    const int* __restrict__ flag, void* __restrict__ outv){
  __shared__ __align__(16) unsigned short Hlds[2][16*LSTM_PAD];
  __shared__ float smH[16][68];      // +4 pad: conflict-light
  int tid = threadIdx.x;
  int lane = tid & 63, wave = tid >> 6;
  int q = lane >> 4, c = lane & 15;
  int s0 = blockIdx.x * 16;

  bf16x8 Bf[4][4];
  #pragma unroll
  for (int g = 0; g < 4; ++g){
    int n = g*64 + wave*16 + c;
    #pragma unroll
    for (int ks = 0; ks < 4; ++ks){
      const float* srcp = (ks < 2) ? (Whh + (size_t)n*64 + ks*32 + q*8)
                                   : (Wih + (size_t)n*64 + (ks-2)*32 + q*8);
      float4 a = ((const float4*)srcp)[0];
      float4 b = ((const float4*)srcp)[1];
      Bf[g][ks] = pack8(a, b);
    }
  }
  float bsum[4];
  #pragma unroll
  for (int g = 0; g < 4; ++g){
    int n = g*64 + wave*16 + c;
    bsum[g] = bih[n] + bhh[n];
  }
  for (int i = tid; i < 16*LSTM_PAD; i += 256) Hlds[0][i] = 0;
  float cst[4] = {0.f, 0.f, 0.f, 0.f};
  __syncthreads();

  int buf = 0;
  for (int t = 0; t < T_; ++t){
    const unsigned short* xr = xinb + ((size_t)(s0 + c)*T_ + t)*64;
    bf16x8 Ax0 = *(const bf16x8*)(xr + q*8);
    bf16x8 Ax1 = *(const bf16x8*)(xr + 32 + q*8);
    const bf16x8* hrow = (const bf16x8*)(Hlds[buf] + c*LSTM_PAD);
    bf16x8 Ah0 = hrow[q];
    bf16x8 Ah1 = hrow[4 + q];

    f32x4 acc[4];
    #pragma unroll
    for (int g = 0; g < 4; ++g){ acc[g][0]=bsum[g]; acc[g][1]=bsum[g]; acc[g][2]=bsum[g]; acc[g][3]=bsum[g]; }
    #pragma unroll
    for (int g = 0; g < 4; ++g) acc[g] = __builtin_amdgcn_mfma_f32_16x16x32_bf16(Ah0, Bf[g][0], acc[g], 0, 0, 0);
    #pragma unroll
    for (int g = 0; g < 4; ++g) acc[g] = __builtin_amdgcn_mfma_f32_16x16x32_bf16(Ah1, Bf[g][1], acc[g], 0, 0, 0);
    #pragma unroll
    for (int g = 0; g < 4; ++g) acc[g] = __builtin_amdgcn_mfma_f32_16x16x32_bf16(Ax0, Bf[g][2], acc[g], 0, 0, 0);
    #pragma unroll
    for (int g = 0; g < 4; ++g) acc[g] = __builtin_amdgcn_mfma_f32_16x16x32_bf16(Ax1, Bf[g][3], acc[g], 0, 0, 0);

    float hv[4];
    #pragma unroll
    for (int r = 0; r < 4; ++r){
      float zi = acc[0][r], zf = acc[1][r], zg = acc[2][r], zo = acc[3][r];
      cst[r] = sigf(zf)*cst[r] + sigf(zi)*tanhfast(zg);
      hv[r] = sigf(zo)*tanhfast(cst[r]);
    }
    if (t == T_-1){
      #pragma unroll
      for (int r = 0; r < 4; ++r)
        smH[q*4 + r][wave*16 + c] = hv[r];
    } else {
      #pragma unroll
      for (int r = 0; r < 4; ++r)
        Hlds[buf^1][(q*4 + r)*LSTM_PAD + wave*16 + c] = (unsigned short)f2bf_rtn(hv[r]);
      __syncthreads();
      buf ^= 1;
    }
  }
  __syncthreads();

  // fused LayerNorm + dense[64,12]; wave w handles seqs 4w..4w+3
  int isbf = *flag;
  #pragma unroll
  for (int si = 0; si < 4; ++si){
    int s = wave*4 + si;
    float h = smH[s][lane];
    float mu = wave_sum(h) * (1.f/64.f);
    float dev = h - mu;
    float var = wave_sum(dev*dev) * (1.f/64.f);
    float hn = dev * rsqrtf(var + 1e-5f) * lng[lane] + lnb[lane];
    smH[s][lane] = hn;       // wave-internal write->read, in-order LDS
    if (lane < 12){
      float o = db[lane];
      #pragma unroll
      for (int k = 0; k < 64; ++k) o = fmaf(smH[s][k], dW[k*12 + lane], o);
      size_t oi = (size_t)(s0 + s)*12 + lane;
      if (isbf) ((unsigned short*)outv)[oi] = (unsigned short)f2bf_rtn(o);
      else      ((float*)outv)[oi] = o;
    }
  }
}

extern "C" void kernel_launch(void* const* d_in, const int* in_sizes, int n_in,
                              void* d_out, int out_size, void* d_ws, size_t ws_size,
                              hipStream_t stream) {
  const int* esrc = (const int*)d_in[1];
  const int* edst = (const int*)d_in[2];

  static const int sizes[18] = {512, 64, 4096, 64, 64, 64, 4096, 64, 64, 64,
                                16384, 16384, 256, 256, 64, 64, 768, 12};
  static const int srcidx[18] = {3, 4, 5, 6, 7, 8, 9, 10, 11, 12,
                                 13, 14, 15, 16, 17, 18, 19, 20};
  ConvArgs ca;
  {
    int acc = 0;
    for (int i = 0; i < 18; ++i){ ca.src[i] = d_in[srcidx[i]]; ca.off[i] = acc; acc += sizes[i]; }
    ca.off[18] = acc;   // == NPARAM_
  }

  float* P     = (float*)d_ws;               // [NPARAM_PAD_]
  float* bufA  = P + NPARAM_PAD_;            // gout (bf16, [GNH] ushort)
  float* bufB  = bufA + (size_t)GNH_/2 + 64; // hbuf(bf16)
  float* esb   = bufB + (size_t)GNH_/2 + 64;
  float* edb   = esb  + (size_t)G_*N_;
  int*   cnt_g = (int*)(edb + (size_t)G_*N_);// [N_]
  int*   slot  = cnt_g + N_;                 // [N_*64]
  int*   flag  = slot + N_*DEGCAP;           // [1]
  float* wcb   = (float*)(flag + 1);         // Wc[512] + bc[64]
  unsigned short* goutb = (unsigned short*)bufA;
  unsigned short* hbuf  = (unsigned short*)bufB;

  const float* pg1b = P + 4672;
  const float* pg1as= P + 4736;
  const float* pg1ad= P + 4800;
  const float* pg2W = P + 4864;
  const float* pg2b = P + 8960;
  const float* pg2as= P + 9024;
  const float* pg2ad= P + 9088;
  const float* pWih = P + 9152;
  const float* pWhh = P + 25536;
  const float* pbih = P + 41920;
  const float* pbhh = P + 42176;
  const float* plng = P + 42432;
  const float* plnb = P + 42496;
  const float* pdW  = P + 42560;
  const float* pdb  = P + 43328;

  prep_kernel<<<172, 256, 0, stream>>>(ca, (const unsigned*)d_in[0],
                                       P, flag, cnt_g, wcb, wcb + 512);

  gat_h1_fused_kernel<<<750, 256, 0, stream>>>(d_in[0], flag, esrc, edst, cnt_g, slot,
                                               wcb, wcb + 512, pg1as, pg1ad, hbuf, esb, edb);
  gat_agg_kernel<<<6000, 256, 0, stream>>>(hbuf, esb, edb, cnt_g, slot, pg1b, goutb);

  gat_h2_mfma_kernel<<<750, 256, 0, stream>>>(goutb, pg2W, pg2as, pg2ad, hbuf, esb, edb);
  gat_agg_kernel<<<6000, 256, 0, stream>>>(hbuf, esb, edb, cnt_g, slot, pg2b, goutb);

  lstm_final_kernel<<<250, 256, 0, stream>>>(goutb, pWih, pWhh, pbih, pbhh,
                                             plng, plnb, pdW, pdb, flag, d_out);
}

// Round 14
// 216.419 us; speedup vs baseline: 1.4916x; 1.0469x over previous
//
#include <hip/hip_runtime.h>
#include <hip/hip_bf16.h>
#include <math.h>

#define B_   2
#define N_   2000
#define T_   24
#define NX_  8
#define H_   64
#define G_   (B_*T_)        // 48 graphs
#define E_   32000
#define BN_  (B_*N_)        // 4000 sequences
#define TH_  (T_*H_)        // 1536
#define NTH_ (N_*T_*H_)     // 3072000
#define GNH_ (G_*N_*H_)     // 6144000
#define NPARAM_ 43340       // canonical fp32 param elements (x excluded)
#define NPARAM_PAD_ 43392
#define LSTM_PAD 72         // padded H-row (bf16 elems): 144B stride, 16B aligned, <=2-way banks
#define DEGCAP 64           // slot capacity per dst node (max binomial deg ~35)

using bf16 = __hip_bfloat16;
typedef short bf16x8 __attribute__((ext_vector_type(8)));
typedef float f32x4  __attribute__((ext_vector_type(4)));

__device__ __forceinline__ float uasf(unsigned u){ return __uint_as_float(u); }
__device__ __forceinline__ float wave_sum(float v){
  #pragma unroll
  for (int o = 32; o > 0; o >>= 1) v += __shfl_xor(v, o, 64);
  return v;
}
__device__ __forceinline__ float fastrcp(float x){ return __builtin_amdgcn_rcpf(x); }
__device__ __forceinline__ float sigf(float x){ return fastrcp(1.f + __expf(-x)); }
__device__ __forceinline__ float tanhfast(float x){ return 1.f - 2.f*fastrcp(1.f + __expf(2.f*x)); }
__device__ __forceinline__ float gelu_exact(float x){ return 0.5f*x*(1.f + erff(x*0.70710678118654752f)); }
__device__ __forceinline__ unsigned f2bf_rtn(float f){
  unsigned u = __float_as_uint(f);
  u += 0x7fffu + ((u >> 16) & 1u);
  return u >> 16;
}
__device__ __forceinline__ bf16x8 pack8(float4 a, float4 b){
  bf16x8 v;
  v[0]=(short)f2bf_rtn(a.x); v[1]=(short)f2bf_rtn(a.y);
  v[2]=(short)f2bf_rtn(a.z); v[3]=(short)f2bf_rtn(a.w);
  v[4]=(short)f2bf_rtn(b.x); v[5]=(short)f2bf_rtn(b.y);
  v[6]=(short)f2bf_rtn(b.z); v[7]=(short)f2bf_rtn(b.w);
  return v;
}

// ---------- prep: dtype detect + param convert + cnt zero + Wc fold, ONE dispatch ----------
// Straggler-free: the Wc/bc fold is lane-parallel over k (wave-reduced dots),
// spread across 9 blocks x 4 waves x 16 outputs. No block does deep serial loads.
struct ConvArgs {
  const void* src[18];
  int off[19];
};
__global__ __launch_bounds__(256) void prep_kernel(
    ConvArgs a, const unsigned* __restrict__ xw,
    float* __restrict__ dst, int* __restrict__ flag,
    int* __restrict__ cnt_g,
    float* __restrict__ wc, float* __restrict__ bc){
  __shared__ int scnt;
  int tid = threadIdx.x;
  if (tid == 0) scnt = 0;
  __syncthreads();
  int c = 0;
  for (int i = tid; i < 4096; i += 256){
    unsigned e = (xw[i] >> 7) & 0xffu;
    if (e >= 100u && e <= 140u) c++;
  }
  atomicAdd(&scnt, c);
  __syncthreads();
  int isbf = (scnt > 3276) ? 1 : 0;
  int bid = blockIdx.x;

  if (bid < 170){
    if (bid == 0 && tid == 0) *flag = isbf;
    int i = bid*256 + tid;
    if (i < NPARAM_){
      int seg = 0;
      while (i >= a.off[seg+1]) seg++;
      int j = i - a.off[seg];
      float v;
      if (isbf) v = uasf(((unsigned)((const unsigned short*)a.src[seg])[j]) << 16);
      else      v = ((const float*)a.src[seg])[j];
      dst[i] = v;
    }
  } else if (bid == 170){
    for (int i = tid; i < N_; i += 256) cnt_g[i] = 0;
  } else {
    // blocks 171..179: Wc = fcW @ g1W (512 outs) + bc = fcb @ g1W (64 outs)
    // one output = one wave-reduced 64-length dot (lane = k index)
    int lane = tid & 63, wave = tid >> 6;
    int b = bid - 171;                   // 0..8
    const unsigned short* fcWu = (const unsigned short*)a.src[0];
    const unsigned short* fcbu = (const unsigned short*)a.src[1];
    const unsigned short* g1Wu = (const unsigned short*)a.src[2];
    const float* fcWf = (const float*)a.src[0];
    const float* fcbf = (const float*)a.src[1];
    const float* g1Wf = (const float*)a.src[2];
    #pragma unroll
    for (int s = 0; s < 16; ++s){
      int o = b*64 + wave*16 + s;        // 0..575
      int r = o >> 6;                    // 0..8 (8 == bias row)
      int n = o & 63;
      float fa, fb;
      if (isbf){
        fa = (r < 8) ? uasf(((unsigned)fcWu[r*64 + lane]) << 16)
                     : uasf(((unsigned)fcbu[lane]) << 16);
        fb = uasf(((unsigned)g1Wu[lane*64 + n]) << 16);
      } else {
        fa = (r < 8) ? fcWf[r*64 + lane] : fcbf[lane];
        fb = g1Wf[lane*64 + n];
      }
      float sv = wave_sum(fa * fb);
      if (lane == 0){
        if (r < 8) wc[r*64 + n] = sv;
        else       bc[n] = sv;
      }
    }
  }
}

// ---------- GAT1 fused: edge-table build (blocks 0..124) + h = x @ Wc + bc via MFMA ----------
__global__ __launch_bounds__(256) void gat_h1_fused_kernel(
    const void* __restrict__ xraw, const int* __restrict__ flag,
    const int* __restrict__ esrc, const int* __restrict__ edst,
    int* __restrict__ cnt_g, int* __restrict__ slot,
    const float* __restrict__ wc, const float* __restrict__ bc,
    const float* __restrict__ asrc, const float* __restrict__ adst,
    unsigned short* __restrict__ hbuf, float* __restrict__ es, float* __restrict__ ed){
  // edge build: 125 blocks x 256 edges, fully parallel, overlapped with MFMA blocks
  if (blockIdx.x < 125){
    int e = blockIdx.x*256 + threadIdx.x;      // exactly covers E_=32000
    int d = edst[e];
    int pos = atomicAdd(&cnt_g[d], 1);
    if (pos < DEGCAP) slot[(d << 6) + pos] = esrc[e];
  }
  int lane = threadIdx.x & 63, wave = threadIdx.x >> 6;
  int q = lane >> 4, c = lane & 15;
  int isbf = *flag;
  bf16x8 Bf[4];                       // B[n=c][k=q*8+j]; only q==0 rows of Wc nonzero
  #pragma unroll
  for (int nt = 0; nt < 4; ++nt){
    bf16x8 v;
    #pragma unroll
    for (int j = 0; j < 8; ++j)
      v[j] = (q == 0) ? (short)f2bf_rtn(wc[j*64 + nt*16 + c]) : (short)0;
    Bf[nt] = v;
  }
  float bcv[4];
  #pragma unroll
  for (int nt = 0; nt < 4; ++nt) bcv[nt] = bc[nt*16 + c];
  float aS[4], aD[4];
  #pragma unroll
  for (int nt = 0; nt < 4; ++nt){ aS[nt] = asrc[nt*16+c]; aD[nt] = adst[nt*16+c]; }

  int w = blockIdx.x*4 + wave;        // 750*4 = 3000 waves, 2 tiles each
  #pragma unroll
  for (int it = 0; it < 2; ++it){
    int tile = w*2 + it;
    int p0 = tile*16;
    int g  = p0 / N_, n0 = p0 - g*N_;
    int bb = g / T_,  tt = g - bb*T_;
    bf16x8 A0;
    #pragma unroll
    for (int j = 0; j < 8; ++j) A0[j] = 0;
    if (q == 0){
      size_t rowelt = ((size_t)(bb*N_ + n0 + c)*T_ + tt)*NX_;
      if (isbf){
        A0 = *(const bf16x8*)((const unsigned short*)xraw + rowelt);
      } else {
        const float4* xr4 = (const float4*)((const float*)xraw + rowelt);
        A0 = pack8(xr4[0], xr4[1]);
      }
    }
    f32x4 acc[4];
    #pragma unroll
    for (int nt = 0; nt < 4; ++nt){ acc[nt][0]=bcv[nt]; acc[nt][1]=bcv[nt]; acc[nt][2]=bcv[nt]; acc[nt][3]=bcv[nt]; }
    #pragma unroll
    for (int nt = 0; nt < 4; ++nt) acc[nt] = __builtin_amdgcn_mfma_f32_16x16x32_bf16(A0, Bf[nt], acc[nt], 0, 0, 0);

    #pragma unroll
    for (int nt = 0; nt < 4; ++nt){
      #pragma unroll
      for (int r = 0; r < 4; ++r)
        hbuf[(size_t)(p0 + q*4 + r)*H_ + nt*16 + c] = (unsigned short)f2bf_rtn(acc[nt][r]);
    }
    #pragma unroll
    for (int r = 0; r < 4; ++r){
      float e1 = acc[0][r]*aS[0] + acc[1][r]*aS[1] + acc[2][r]*aS[2] + acc[3][r]*aS[3];
      float e2 = acc[0][r]*aD[0] + acc[1][r]*aD[1] + acc[2][r]*aD[2] + acc[3][r]*aD[3];
      #pragma unroll
      for (int o = 8; o > 0; o >>= 1){
        e1 += __shfl_xor(e1, o, 64);
        e2 += __shfl_xor(e2, o, 64);
      }
      if (c == 0){
        es[p0 + q*4 + r] = e1;
        ed[p0 + q*4 + r] = e2;
      }
    }
  }
}

// ---------- GAT2 h = gout1(bf16) @ W via MFMA (scrambled raw-reshape reads) ----------
__global__ __launch_bounds__(256) void gat_h2_mfma_kernel(
    const unsigned short* __restrict__ xinb, const float* __restrict__ W,
    const float* __restrict__ asrc, const float* __restrict__ adst,
    unsigned short* __restrict__ hbuf, float* __restrict__ es, float* __restrict__ ed){
  int lane = threadIdx.x & 63, wave = threadIdx.x >> 6;
  int q = lane >> 4, c = lane & 15;
  bf16x8 Bf[4][2];
  #pragma unroll
  for (int nt = 0; nt < 4; ++nt){
    #pragma unroll
    for (int ks = 0; ks < 2; ++ks){
      bf16x8 v;
      #pragma unroll
      for (int j = 0; j < 8; ++j)
        v[j] = (short)f2bf_rtn(W[(ks*32 + q*8 + j)*H_ + nt*16 + c]);
      Bf[nt][ks] = v;
    }
  }
  float aS[4], aD[4];
  #pragma unroll
  for (int nt = 0; nt < 4; ++nt){ aS[nt] = asrc[nt*16+c]; aD[nt] = adst[nt*16+c]; }

  int w = blockIdx.x*4 + wave;
  #pragma unroll
  for (int it = 0; it < 2; ++it){
    int tile = w*2 + it;
    int p0 = tile*16;
    int p  = p0 + c;
    int g = p / N_, n = p - g*N_;
    int bb = g / T_, t = g - bb*T_;
    const unsigned short* xr = xinb + (size_t)bb*NTH_ + (size_t)n*TH_ + (size_t)t*H_;
    bf16x8 A0 = *(const bf16x8*)(xr + q*8);
    bf16x8 A1 = *(const bf16x8*)(xr + 32 + q*8);

    f32x4 acc[4];
    #pragma unroll
    for (int nt = 0; nt < 4; ++nt){ acc[nt][0]=0.f; acc[nt][1]=0.f; acc[nt][2]=0.f; acc[nt][3]=0.f; }
    #pragma unroll
    for (int nt = 0; nt < 4; ++nt) acc[nt] = __builtin_amdgcn_mfma_f32_16x16x32_bf16(A0, Bf[nt][0], acc[nt], 0, 0, 0);
    #pragma unroll
    for (int nt = 0; nt < 4; ++nt) acc[nt] = __builtin_amdgcn_mfma_f32_16x16x32_bf16(A1, Bf[nt][1], acc[nt], 0, 0, 0);

    #pragma unroll
    for (int nt = 0; nt < 4; ++nt){
      #pragma unroll
      for (int r = 0; r < 4; ++r)
        hbuf[(size_t)(p0 + q*4 + r)*H_ + nt*16 + c] = (unsigned short)f2bf_rtn(acc[nt][r]);
    }
    #pragma unroll
    for (int r = 0; r < 4; ++r){
      float e1 = acc[0][r]*aS[0] + acc[1][r]*aS[1] + acc[2][r]*aS[2] + acc[3][r]*aS[3];
      float e2 = acc[0][r]*aD[0] + acc[1][r]*aD[1] + acc[2][r]*aD[2] + acc[3][r]*aD[3];
      #pragma unroll
      for (int o = 8; o > 0; o >>= 1){
        e1 += __shfl_xor(e1, o, 64);
        e2 += __shfl_xor(e2, o, 64);
      }
      if (c == 0){
        es[p0 + q*4 + r] = e1;
        ed[p0 + q*4 + r] = e2;
      }
    }
  }
}

// ---------- GAT aggregate: 4 (g,d)/wave, 4 chan/lane uint2 gathers, bf16 output ----------
__global__ __launch_bounds__(256) void gat_agg_kernel(
    const unsigned short* __restrict__ hbuf, const float* __restrict__ es, const float* __restrict__ ed,
    const int* __restrict__ cnt_g, const int* __restrict__ slot,
    const float* __restrict__ bias, unsigned short* __restrict__ goutb){
  int lane = threadIdx.x & 63, wave = threadIdx.x >> 6;
  int qd = lane >> 4, ln = lane & 15;
  int gd = (blockIdx.x*4 + wave)*4 + qd;   // 6000 blocks -> 96000 pairs
  int g = gd / N_, d = gd - g*N_;
  int start = d << 6;
  int deg = min(cnt_g[d], DEGCAP);
  const float* esg = es + (size_t)g*N_;
  float edv = ed[(size_t)g*N_ + d];
  const char* hg = (const char*)(hbuf + (size_t)g*N_*H_);
  unsigned lanoff = ((unsigned)ln) << 3;   // 8 B per lane = 4 bf16 channels
  int hbase = qd << 4;
  int dm = deg;                             // wave-uniform max degree over 4 groups
  dm = max(dm, __shfl_xor(dm, 16, 64));
  dm = max(dm, __shfl_xor(dm, 32, 64));
  int NC = (dm + 15) >> 4;                  // chunks of 16, <=4

  // pass 1: load slot ids + scores into registers (all loads independent)
  int svk[4]; float sck[4];
  #pragma unroll
  for (int k = 0; k < 4; ++k){ svk[k] = 0; sck[k] = -1e30f; }
  #pragma unroll
  for (int k = 0; k < 4; ++k){
    int i = k*16 + ln;
    if (k < NC && i < deg) svk[k] = slot[start + i];
  }
  #pragma unroll
  for (int k = 0; k < 4; ++k){
    int i = k*16 + ln;
    if (k < NC && i < deg){
      float e = esg[svk[k]] + edv;
      sck[k] = e > 0.f ? e : 0.2f*e;
    }
  }
  float m = fmaxf(fmaxf(sck[0], sck[1]), fmaxf(sck[2], sck[3]));
  #pragma unroll
  for (int o = 8; o > 0; o >>= 1) m = fmaxf(m, __shfl_xor(m, o, 64));
  // pass 2: register-only exp + sum
  float exk[4]; float ssum = 0.f;
  #pragma unroll
  for (int k = 0; k < 4; ++k){
    int i = k*16 + ln;
    float e = (k < NC && i < deg) ? __expf(sck[k] - m) : 0.f;
    exk[k] = e; ssum += e;
  }
  #pragma unroll
  for (int o = 8; o > 0; o >>= 1) ssum += __shfl_xor(ssum, o, 64);
  float inv = fastrcp(ssum + 1e-16f);
  unsigned pwk[4];
  #pragma unroll
  for (int k = 0; k < 4; ++k)
    pwk[k] = (f2bf_rtn(exk[k]*inv) << 16) | (unsigned)svk[k];

  // pass 3: gather h rows (uint2 = 4 channels) with shfl-broadcast ids
  float a0 = 0.f, a1 = 0.f, a2 = 0.f, a3 = 0.f;
  for (int k = 0; k < NC; ++k){
    unsigned pw = pwk[k];
    int myrem = deg - k*16;                 // per-group remaining (predicate only)
    int remw = dm - k*16; if (remw > 16) remw = 16;   // wave-uniform trip
    for (int j0 = 0; j0 < remw; j0 += 8){
      unsigned wv[8]; float aa[8]; unsigned off[8];
      #pragma unroll
      for (int u = 0; u < 8; ++u){
        int j = j0 + u;
        wv[u] = (unsigned)__shfl((int)pw, hbase + j, 64);
        aa[u] = (j < myrem) ? uasf(wv[u] & 0xffff0000u) : 0.f;
        off[u] = ((wv[u] & 0xffffu) << 7) + lanoff;
      }
      uint2 hv[8];
      #pragma unroll
      for (int u = 0; u < 8; ++u)
        hv[u] = *(const uint2*)(hg + off[u]);
      #pragma unroll
      for (int u = 0; u < 8; ++u){
        a0 = fmaf(aa[u], uasf(hv[u].x << 16), a0);
        a1 = fmaf(aa[u], uasf(hv[u].x & 0xffff0000u), a1);
        a2 = fmaf(aa[u], uasf(hv[u].y << 16), a2);
        a3 = fmaf(aa[u], uasf(hv[u].y & 0xffff0000u), a3);
      }
    }
  }
  float4 bv = ((const float4*)bias)[ln];
  uint2 ov;
  ov.x = f2bf_rtn(gelu_exact(a0 + bv.x)) | (f2bf_rtn(gelu_exact(a1 + bv.y)) << 16);
  ov.y = f2bf_rtn(gelu_exact(a2 + bv.z)) | (f2bf_rtn(gelu_exact(a3 + bv.w)) << 16);
  ((uint2*)(goutb + (size_t)gd*H_))[ln] = ov;
}

// ---------- LSTM via MFMA (bf16 x input, single-barrier dbuf) + fused LN/dense ----------
__global__ __launch_bounds__(256) void lstm_final_kernel(
    const unsigned short* __restrict__ xinb,  // bf16 flat [BN*T, 64]: row = seq*T + t
    const float* __restrict__ Wih,   // [256][64] row-major
    const float* __restrict__ Whh,   // [256][64] row-major
    const float* __restrict__ bih, const float* __restrict__ bhh,
    const float* __restrict__ lng, const float* __restrict__ lnb,
    const float* __restrict__ dW, const float* __restrict__ db,
    const int* __restrict__ flag, void* __restrict__ outv){
  __shared__ __align__(16) unsigned short Hlds[2][16*LSTM_PAD];
  __shared__ float smH[16][68];      // +4 pad: conflict-light
  int tid = threadIdx.x;
  int lane = tid & 63, wave = tid >> 6;
  int q = lane >> 4, c = lane & 15;
  int s0 = blockIdx.x * 16;

  bf16x8 Bf[4][4];
  #pragma unroll
  for (int g = 0; g < 4; ++g){
    int n = g*64 + wave*16 + c;
    #pragma unroll
    for (int ks = 0; ks < 4; ++ks){
      const float* srcp = (ks < 2) ? (Whh + (size_t)n*64 + ks*32 + q*8)
                                   : (Wih + (size_t)n*64 + (ks-2)*32 + q*8);
      float4 a = ((const float4*)srcp)[0];
      float4 b = ((const float4*)srcp)[1];
      Bf[g][ks] = pack8(a, b);
    }
  }
  float bsum[4];
  #pragma unroll
  for (int g = 0; g < 4; ++g){
    int n = g*64 + wave*16 + c;
    bsum[g] = bih[n] + bhh[n];
  }
  for (int i = tid; i < 16*LSTM_PAD; i += 256) Hlds[0][i] = 0;
  float cst[4] = {0.f, 0.f, 0.f, 0.f};
  __syncthreads();

  int buf = 0;
  for (int t = 0; t < T_; ++t){
    const unsigned short* xr = xinb + ((size_t)(s0 + c)*T_ + t)*64;
    bf16x8 Ax0 = *(const bf16x8*)(xr + q*8);
    bf16x8 Ax1 = *(const bf16x8*)(xr + 32 + q*8);
    const bf16x8* hrow = (const bf16x8*)(Hlds[buf] + c*LSTM_PAD);
    bf16x8 Ah0 = hrow[q];
    bf16x8 Ah1 = hrow[4 + q];

    f32x4 acc[4];
    #pragma unroll
    for (int g = 0; g < 4; ++g){ acc[g][0]=bsum[g]; acc[g][1]=bsum[g]; acc[g][2]=bsum[g]; acc[g][3]=bsum[g]; }
    #pragma unroll
    for (int g = 0; g < 4; ++g) acc[g] = __builtin_amdgcn_mfma_f32_16x16x32_bf16(Ah0, Bf[g][0], acc[g], 0, 0, 0);
    #pragma unroll
    for (int g = 0; g < 4; ++g) acc[g] = __builtin_amdgcn_mfma_f32_16x16x32_bf16(Ah1, Bf[g][1], acc[g], 0, 0, 0);
    #pragma unroll
    for (int g = 0; g < 4; ++g) acc[g] = __builtin_amdgcn_mfma_f32_16x16x32_bf16(Ax0, Bf[g][2], acc[g], 0, 0, 0);
    #pragma unroll
    for (int g = 0; g < 4; ++g) acc[g] = __builtin_amdgcn_mfma_f32_16x16x32_bf16(Ax1, Bf[g][3], acc[g], 0, 0, 0);

    float hv[4];
    #pragma unroll
    for (int r = 0; r < 4; ++r){
      float zi = acc[0][r], zf = acc[1][r], zg = acc[2][r], zo = acc[3][r];
      cst[r] = sigf(zf)*cst[r] + sigf(zi)*tanhfast(zg);
      hv[r] = sigf(zo)*tanhfast(cst[r]);
    }
    if (t == T_-1){
      #pragma unroll
      for (int r = 0; r < 4; ++r)
        smH[q*4 + r][wave*16 + c] = hv[r];
    } else {
      #pragma unroll
      for (int r = 0; r < 4; ++r)
        Hlds[buf^1][(q*4 + r)*LSTM_PAD + wave*16 + c] = (unsigned short)f2bf_rtn(hv[r]);
      __syncthreads();
      buf ^= 1;
    }
  }
  __syncthreads();

  // fused LayerNorm + dense[64,12]; wave w handles seqs 4w..4w+3
  int isbf = *flag;
  #pragma unroll
  for (int si = 0; si < 4; ++si){
    int s = wave*4 + si;
    float h = smH[s][lane];
    float mu = wave_sum(h) * (1.f/64.f);
    float dev = h - mu;
    float var = wave_sum(dev*dev) * (1.f/64.f);
    float hn = dev * rsqrtf(var + 1e-5f) * lng[lane] + lnb[lane];
    smH[s][lane] = hn;       // wave-internal write->read, in-order LDS
    if (lane < 12){
      float o = db[lane];
      #pragma unroll
      for (int k = 0; k < 64; ++k) o = fmaf(smH[s][k], dW[k*12 + lane], o);
      size_t oi = (size_t)(s0 + s)*12 + lane;
      if (isbf) ((unsigned short*)outv)[oi] = (unsigned short)f2bf_rtn(o);
      else      ((float*)outv)[oi] = o;
    }
  }
}

extern "C" void kernel_launch(void* const* d_in, const int* in_sizes, int n_in,
                              void* d_out, int out_size, void* d_ws, size_t ws_size,
                              hipStream_t stream) {
  const int* esrc = (const int*)d_in[1];
  const int* edst = (const int*)d_in[2];

  static const int sizes[18] = {512, 64, 4096, 64, 64, 64, 4096, 64, 64, 64,
                                16384, 16384, 256, 256, 64, 64, 768, 12};
  static const int srcidx[18] = {3, 4, 5, 6, 7, 8, 9, 10, 11, 12,
                                 13, 14, 15, 16, 17, 18, 19, 20};
  ConvArgs ca;
  {
    int acc = 0;
    for (int i = 0; i < 18; ++i){ ca.src[i] = d_in[srcidx[i]]; ca.off[i] = acc; acc += sizes[i]; }
    ca.off[18] = acc;   // == NPARAM_
  }

  float* P     = (float*)d_ws;               // [NPARAM_PAD_]
  float* bufA  = P + NPARAM_PAD_;            // gout (bf16, [GNH] ushort)
  float* bufB  = bufA + (size_t)GNH_/2 + 64; // hbuf(bf16)
  float* esb   = bufB + (size_t)GNH_/2 + 64;
  float* edb   = esb  + (size_t)G_*N_;
  int*   cnt_g = (int*)(edb + (size_t)G_*N_);// [N_]
  int*   slot  = cnt_g + N_;                 // [N_*64]
  int*   flag  = slot + N_*DEGCAP;           // [1]
  float* wcb   = (float*)(flag + 1);         // Wc[512] + bc[64]
  unsigned short* goutb = (unsigned short*)bufA;
  unsigned short* hbuf  = (unsigned short*)bufB;

  const float* pg1b = P + 4672;
  const float* pg1as= P + 4736;
  const float* pg1ad= P + 4800;
  const float* pg2W = P + 4864;
  const float* pg2b = P + 8960;
  const float* pg2as= P + 9024;
  const float* pg2ad= P + 9088;
  const float* pWih = P + 9152;
  const float* pWhh = P + 25536;
  const float* pbih = P + 41920;
  const float* pbhh = P + 42176;
  const float* plng = P + 42432;
  const float* plnb = P + 42496;
  const float* pdW  = P + 42560;
  const float* pdb  = P + 43328;

  prep_kernel<<<180, 256, 0, stream>>>(ca, (const unsigned*)d_in[0],
                                       P, flag, cnt_g, wcb, wcb + 512);

  gat_h1_fused_kernel<<<750, 256, 0, stream>>>(d_in[0], flag, esrc, edst, cnt_g, slot,
                                               wcb, wcb + 512, pg1as, pg1ad, hbuf, esb, edb);
  gat_agg_kernel<<<6000, 256, 0, stream>>>(hbuf, esb, edb, cnt_g, slot, pg1b, goutb);

  gat_h2_mfma_kernel<<<750, 256, 0, stream>>>(goutb, pg2W, pg2as, pg2ad, hbuf, esb, edb);
  gat_agg_kernel<<<6000, 256, 0, stream>>>(hbuf, esb, edb, cnt_g, slot, pg2b, goutb);

  lstm_final_kernel<<<250, 256, 0, stream>>>(goutb, pWih, pWhh, pbih, pbhh,
                                             plng, plnb, pdW, pdb, flag, d_out);
}